// Round 1
// baseline (2169.680 us; speedup 1.0000x reference)
//
#include <hip/hip_runtime.h>
#include <math.h>

#define DM 768
#define NH 8
#define HD 96
#define BQ 4
#define LQ 1024
#define LK 4096

// C[row,j] = sum_d X[row,d] * W[j,d] + bias[j]   (i.e. X @ W.T + b)
// MODE 0: plain row-major out[row*DM + j]
// MODE 1: RoPE epilogue, write (B,H,L,HD)
// MODE 2: no RoPE, write (B,H,L,HD)
template<int MODE>
__global__ __launch_bounds__(256)
void gemm_rope(const float* __restrict__ X, const float* __restrict__ W,
               const float* __restrict__ bias, const float* __restrict__ coords,
               float* __restrict__ out, int L)
{
    __shared__ float Xs[32][68];   // [k][row], pad 68 keeps float4 rows 16B-aligned
    __shared__ float Ws[32][68];   // [k][col]
    __shared__ float Cs[64][65];   // epilogue tile (RoPE partner exchange)

    const int tid  = threadIdx.x;
    const int col0 = blockIdx.x * 64;
    const int row0 = blockIdx.y * 64;
    const int tx = tid & 15, ty = tid >> 4;

    float acc[4][4] = {};

    for (int k0 = 0; k0 < DM; k0 += 32) {
        #pragma unroll
        for (int e = 0; e < 8; ++e) {
            int idx = tid + 256 * e;           // 0..2047 = 64 rows x 32 k
            int lr = idx >> 5, lk = idx & 31;
            Xs[lk][lr] = X[(size_t)(row0 + lr) * DM + k0 + lk];
            Ws[lk][lr] = W[(size_t)(col0 + lr) * DM + k0 + lk];
        }
        __syncthreads();
        #pragma unroll
        for (int kk = 0; kk < 32; ++kk) {
            float4 a4 = *(const float4*)&Xs[kk][ty * 4];
            float4 b4 = *(const float4*)&Ws[kk][tx * 4];
            float a[4] = {a4.x, a4.y, a4.z, a4.w};
            float b[4] = {b4.x, b4.y, b4.z, b4.w};
            #pragma unroll
            for (int i = 0; i < 4; ++i)
                #pragma unroll
                for (int j = 0; j < 4; ++j)
                    acc[i][j] = fmaf(a[i], b[j], acc[i][j]);
        }
        __syncthreads();
    }

    // stash tile (+bias) to LDS so RoPE can read the j^16 partner column
    #pragma unroll
    for (int i = 0; i < 4; ++i)
        #pragma unroll
        for (int j = 0; j < 4; ++j)
            Cs[ty*4 + i][tx*4 + j] = acc[i][j] + bias[col0 + tx*4 + j];
    __syncthreads();

    #pragma unroll
    for (int e = 0; e < 16; ++e) {
        int idx = tid + 256 * e;
        int lr = idx >> 6, lc = idx & 63;
        int row = row0 + lr, j = col0 + lc;
        float val = Cs[lr][lc];
        if (MODE == 0) {
            out[(size_t)row * DM + j] = val;
        } else {
            int h = j / HD;
            int t = j % HD;
            if (MODE == 1) {
                int a  = t >> 5;          // chunk 0..2 (HD=96 = 3*32)
                int u  = t & 31;          // pos in chunk; chunks are globally 32-aligned
                int i_ = u & 15;          // freq index
                float freq  = exp2f(-(float)i_ * 0.83048202372184058696f); // 10000^(-i/16)
                float theta = coords[(size_t)row * 3 + a] * freq;
                float cs = cosf(theta), sn = sinf(theta);
                float partner = Cs[lr][lc ^ 16];  // tile is 64-aligned -> partner in tile
                val = (u < 16) ? (val * cs - partner * sn)
                               : (partner * sn + val * cs);
            }
            int b = row / L, l = row % L;
            out[(((size_t)b * NH + h) * L + l) * HD + t] = val;
        }
    }
}

// Flash attention: 1 block = (b, h, 32-query tile); K/V tiles of 32 in LDS.
// thread -> (row r = tid>>3, group lane g = tid&7); scores for k-rows g+8m.
__global__ __launch_bounds__(256)
void attn(const float* __restrict__ q, const float* __restrict__ k,
          const float* __restrict__ v, float* __restrict__ ctx)
{
    __shared__ float qs[32][100];  // pad 100: float4-aligned rows
    __shared__ float ks[32][100];
    __shared__ float vs[32][100];
    __shared__ float Ss[32][36];

    const int tid = threadIdx.x;
    const int bid = blockIdx.x;
    const int qt = bid & 31;           // Lq/32 = 32 tiles
    const int h  = (bid >> 5) & 7;
    const int b  = bid >> 8;

    const float* qbase = q + (((size_t)b * NH + h) * LQ + qt * 32) * HD;
    const float* kbase = k + ((size_t)b * NH + h) * LK * HD;
    const float* vbase = v + ((size_t)b * NH + h) * LK * HD;

    #pragma unroll
    for (int e = 0; e < 12; ++e) {     // 32*96/256 = 12
        int idx = tid + 256 * e;
        qs[idx / 96][idx % 96] = qbase[idx];
    }

    const int r = tid >> 3;
    const int g = tid & 7;

    float m_prev = -1e30f, l_sum = 0.f;
    float acc[12] = {};
    const float scale = 0.10206207261596575f;  // 1/sqrt(96)

    for (int kt = 0; kt < LK; kt += 32) {
        #pragma unroll
        for (int e = 0; e < 12; ++e) {
            int idx = tid + 256 * e;
            int rr = idx / 96, d = idx % 96;
            ks[rr][d] = kbase[(size_t)kt * HD + idx];
            vs[rr][d] = vbase[(size_t)kt * HD + idx];
        }
        __syncthreads();   // covers qs on first iter too

        // S[r][g+8m] = q[r] . k[g+8m]   (k-row = g+8m: 8 lanes hit distinct banks)
        float s4[4] = {0.f, 0.f, 0.f, 0.f};
        #pragma unroll 8
        for (int d = 0; d < 96; d += 4) {
            float4 q4 = *(const float4*)&qs[r][d];
            #pragma unroll
            for (int m = 0; m < 4; ++m) {
                float4 k4 = *(const float4*)&ks[g + 8*m][d];
                s4[m] = fmaf(q4.x, k4.x, s4[m]);
                s4[m] = fmaf(q4.y, k4.y, s4[m]);
                s4[m] = fmaf(q4.z, k4.z, s4[m]);
                s4[m] = fmaf(q4.w, k4.w, s4[m]);
            }
        }
        float mt = -1e30f;
        #pragma unroll
        for (int m = 0; m < 4; ++m) { s4[m] *= scale; mt = fmaxf(mt, s4[m]); }
        #pragma unroll
        for (int o = 1; o < 8; o <<= 1) mt = fmaxf(mt, __shfl_xor(mt, o, 64));
        float m_new = fmaxf(m_prev, mt);
        float alpha = __expf(m_prev - m_new);
        float psum = 0.f;
        #pragma unroll
        for (int m = 0; m < 4; ++m) {
            float p = __expf(s4[m] - m_new);
            Ss[r][g + 8*m] = p;
            psum += p;
        }
        #pragma unroll
        for (int o = 1; o < 8; o <<= 1) psum += __shfl_xor(psum, o, 64);
        l_sum = l_sum * alpha + psum;
        m_prev = m_new;
        #pragma unroll
        for (int j = 0; j < 12; ++j) acc[j] *= alpha;
        __syncthreads();   // Ss visible to all 8 lanes of each row-group

        #pragma unroll 4
        for (int kk = 0; kk < 32; ++kk) {
            float p = Ss[r][kk];
            #pragma unroll
            for (int j4 = 0; j4 < 3; ++j4) {
                float4 v4 = *(const float4*)&vs[kk][g*12 + j4*4];
                acc[j4*4+0] = fmaf(p, v4.x, acc[j4*4+0]);
                acc[j4*4+1] = fmaf(p, v4.y, acc[j4*4+1]);
                acc[j4*4+2] = fmaf(p, v4.z, acc[j4*4+2]);
                acc[j4*4+3] = fmaf(p, v4.w, acc[j4*4+3]);
            }
        }
        __syncthreads();   // protect ks/vs/Ss before next tile's writes
    }

    float inv_l = 1.f / l_sum;
    float* cbase = ctx + ((size_t)b * LQ + qt*32 + r) * DM + h * HD + g * 12;
    #pragma unroll
    for (int j = 0; j < 12; ++j) cbase[j] = acc[j] * inv_l;
}

extern "C" void kernel_launch(void* const* d_in, const int* in_sizes, int n_in,
                              void* d_out, int out_size, void* d_ws, size_t ws_size,
                              hipStream_t stream)
{
    const float* query = (const float*)d_in[0];
    const float* key   = (const float*)d_in[1];
    const float* value = (const float*)d_in[2];
    const float* cq    = (const float*)d_in[3];
    const float* ck    = (const float*)d_in[4];
    const float* Wq    = (const float*)d_in[5];
    const float* bqv   = (const float*)d_in[6];
    const float* Wk    = (const float*)d_in[7];
    const float* bkv   = (const float*)d_in[8];
    const float* Wv    = (const float*)d_in[9];
    const float* bvv   = (const float*)d_in[10];
    const float* Wo    = (const float*)d_in[11];
    const float* bov   = (const float*)d_in[12];
    float* out = (float*)d_out;

    float* qws = (float*)d_ws;                                // B*H*LQ*HD = 3,145,728 f
    float* kws = qws + (size_t)BQ * NH * LQ * HD;             // B*H*LK*HD = 12,582,912 f
    float* vws = kws + (size_t)BQ * NH * LK * HD;
    float* ctx = vws + (size_t)BQ * NH * LK * HD;             // B*LQ*DM   = 3,145,728 f
    // total 31,457,280 floats = 120 MB of d_ws

    gemm_rope<1><<<dim3(DM/64, BQ*LQ/64), 256, 0, stream>>>(query, Wq, bqv, cq, qws, LQ);
    gemm_rope<1><<<dim3(DM/64, BQ*LK/64), 256, 0, stream>>>(key,   Wk, bkv, ck, kws, LK);
    gemm_rope<2><<<dim3(DM/64, BQ*LK/64), 256, 0, stream>>>(value, Wv, bvv, nullptr, vws, LK);
    attn<<<BQ * NH * (LQ/32), 256, 0, stream>>>(qws, kws, vws, ctx);
    gemm_rope<0><<<dim3(DM/64, BQ*LQ/64), 256, 0, stream>>>(ctx, Wo, bov, nullptr, out, LQ);
}

// Round 2
// 1028.142 us; speedup vs baseline: 2.1103x; 2.1103x over previous
//
#include <hip/hip_runtime.h>
#include <math.h>

#define DM 768
#define NH 8
#define HD 96
#define BQ 4
#define LQ 1024
#define LK 4096

typedef unsigned short ushort;
typedef __attribute__((ext_vector_type(8))) short short8v;
typedef __attribute__((ext_vector_type(4))) float float4v;

static __device__ __forceinline__ ushort f2bf(float x) {
    union { float f; unsigned int u; } c; c.f = x;
    unsigned int u = c.u;
    u += ((u >> 16) & 1u) + 0x7fffu;   // RNE
    return (ushort)(u >> 16);
}

// C[row,j] = sum_d X[row,d] * W[j,d] + bias[j]   (X @ W.T + b)
// MODE 0: fp32 row-major out[row*DM + j]
// MODE 1: RoPE epilogue, write bf16 (B,H,L,HD)
// MODE 2: no RoPE, write bf16 (B,H,L,HD)
template<int MODE>
__global__ __launch_bounds__(256)
void gemm_rope(const float* __restrict__ X, const float* __restrict__ W,
               const float* __restrict__ bias, const float* __restrict__ coords,
               void* __restrict__ out, int L)
{
    __shared__ float Xs[32][68];
    __shared__ float Ws[32][68];
    __shared__ float Cs[64][65];

    const int tid  = threadIdx.x;
    const int col0 = blockIdx.x * 64;
    const int row0 = blockIdx.y * 64;
    const int tx = tid & 15, ty = tid >> 4;

    float acc[4][4] = {};

    for (int k0 = 0; k0 < DM; k0 += 32) {
        #pragma unroll
        for (int e = 0; e < 8; ++e) {
            int idx = tid + 256 * e;
            int lr = idx >> 5, lk = idx & 31;
            Xs[lk][lr] = X[(size_t)(row0 + lr) * DM + k0 + lk];
            Ws[lk][lr] = W[(size_t)(col0 + lr) * DM + k0 + lk];
        }
        __syncthreads();
        #pragma unroll
        for (int kk = 0; kk < 32; ++kk) {
            float4 a4 = *(const float4*)&Xs[kk][ty * 4];
            float4 b4 = *(const float4*)&Ws[kk][tx * 4];
            float a[4] = {a4.x, a4.y, a4.z, a4.w};
            float b[4] = {b4.x, b4.y, b4.z, b4.w};
            #pragma unroll
            for (int i = 0; i < 4; ++i)
                #pragma unroll
                for (int j = 0; j < 4; ++j)
                    acc[i][j] = fmaf(a[i], b[j], acc[i][j]);
        }
        __syncthreads();
    }

    #pragma unroll
    for (int i = 0; i < 4; ++i)
        #pragma unroll
        for (int j = 0; j < 4; ++j)
            Cs[ty*4 + i][tx*4 + j] = acc[i][j] + bias[col0 + tx*4 + j];
    __syncthreads();

    #pragma unroll
    for (int e = 0; e < 16; ++e) {
        int idx = tid + 256 * e;
        int lr = idx >> 6, lc = idx & 63;
        int row = row0 + lr, j = col0 + lc;
        float val = Cs[lr][lc];
        if (MODE == 0) {
            ((float*)out)[(size_t)row * DM + j] = val;
        } else {
            int h = j / HD;
            int t = j % HD;
            if (MODE == 1) {
                int a  = t >> 5;
                int u  = t & 31;
                int i_ = u & 15;
                float freq  = exp2f(-(float)i_ * 0.83048202372184058696f); // 10000^(-i/16)
                float theta = coords[(size_t)row * 3 + a] * freq;
                float cs = cosf(theta), sn = sinf(theta);
                float partner = Cs[lr][lc ^ 16];
                val = (u < 16) ? (val * cs - partner * sn)
                               : (partner * sn + val * cs);
            }
            int b = row / L, l = row % L;
            ((ushort*)out)[(((size_t)b * NH + h) * L + l) * HD + t] = f2bf(val);
        }
    }
}

// bf16 (B,H,LK,96) -> bf16 (B,H,96,LK)
__global__ __launch_bounds__(256)
void transpose_v(const ushort* __restrict__ v, ushort* __restrict__ vt)
{
    __shared__ ushort t[32][34];
    const int k0 = blockIdx.x * 32;
    const int d0 = blockIdx.y * 32;
    const size_t ib = (size_t)blockIdx.z * LK * HD;
    const size_t ob = (size_t)blockIdx.z * HD * LK;
    const int c = threadIdx.x & 31, r8 = threadIdx.x >> 5;
    #pragma unroll
    for (int j = 0; j < 4; ++j)
        t[r8 + 8*j][c] = v[ib + (size_t)(k0 + r8 + 8*j) * HD + d0 + c];
    __syncthreads();
    #pragma unroll
    for (int j = 0; j < 4; ++j)
        vt[ob + (size_t)(d0 + r8 + 8*j) * LK + k0 + c] = t[c][r8 + 8*j];
}

// MFMA flash attention. Block = 256 thr (4 waves) x 64 q-rows; wave owns 16 rows.
// KV tiles of 64. q,k bf16 row-major (B,H,L,96); vt bf16 (B,H,96,LK); ctx fp32.
__global__ __launch_bounds__(256)
void attn_mfma(const ushort* __restrict__ q, const ushort* __restrict__ k,
               const ushort* __restrict__ vt, float* __restrict__ ctx)
{
    __shared__ ushort Ks[64][104];    // keys x d, stride 104: uniform bank-quad spread
    __shared__ ushort Vs[96][72];     // d x keys
    __shared__ ushort Ps[4][16][72];  // per-wave P tile (16 q x 64 k)

    const int tid  = threadIdx.x;
    const int w    = tid >> 6;
    const int lane = tid & 63;
    const int l15  = lane & 15;
    const int lg   = lane >> 4;

    const int qt = blockIdx.x;        // 16 tiles of 64 q-rows
    const int bh = blockIdx.y;        // b*NH + h

    const ushort* qg = q  + ((size_t)bh * LQ + qt*64 + w*16 + l15) * HD;
    const ushort* kg = k  + (size_t)bh * LK * HD;
    const ushort* vg = vt + (size_t)bh * HD * LK;

    // Q fragments hoisted: A row = lane&15, k = (lane>>4)*8 + i (contiguous 8)
    short8v aq[3];
    #pragma unroll
    for (int dc = 0; dc < 3; ++dc)
        aq[dc] = *(const short8v*)(qg + dc*32 + lg*8);

    float4v o[6];
    float m_r[4], l_r[4];
    #pragma unroll
    for (int dt = 0; dt < 6; ++dt) o[dt] = (float4v)0.f;
    #pragma unroll
    for (int r = 0; r < 4; ++r) { m_r[r] = -1e30f; l_r[r] = 0.f; }

    const float scale = 0.10206207261596575f;  // 1/sqrt(96)

    for (int kt = 0; kt < LK; kt += 64) {
        // ---- stage K (64x96) and Vt (96x64), both bf16, 16B chunks ----
        #pragma unroll
        for (int j = 0; j < 3; ++j) {
            int c = tid + 256*j;                 // 768 chunks, linear in memory
            int key = c / 12, d8 = c % 12;
            *(short8v*)&Ks[key][d8*8] =
                *(const short8v*)(kg + (size_t)(kt + key) * HD + d8*8);
        }
        #pragma unroll
        for (int j = 0; j < 3; ++j) {
            int c = tid + 256*j;
            int d = c >> 3, k8 = c & 7;
            *(short8v*)&Vs[d][k8*8] =
                *(const short8v*)(vg + (size_t)d * LK + kt + k8*8);
        }
        __syncthreads();

        // ---- S = Q K^T : 16 x 64 per wave (4 col-tiles x 3 k-chunks) ----
        float4v s[4];
        #pragma unroll
        for (int nt = 0; nt < 4; ++nt) {
            s[nt] = (float4v)0.f;
            #pragma unroll
            for (int dc = 0; dc < 3; ++dc) {
                short8v bk = *(const short8v*)&Ks[nt*16 + l15][dc*32 + lg*8];
                s[nt] = __builtin_amdgcn_mfma_f32_16x16x32_bf16(aq[dc], bk, s[nt], 0, 0, 0);
            }
        }

        // ---- online softmax (rows r = 4*lg + reg; reduce over lanes 0-15 of group) ----
        float mt[4];
        #pragma unroll
        for (int r = 0; r < 4; ++r) mt[r] = -1e30f;
        #pragma unroll
        for (int nt = 0; nt < 4; ++nt)
            #pragma unroll
            for (int r = 0; r < 4; ++r) {
                s[nt][r] *= scale;
                mt[r] = fmaxf(mt[r], s[nt][r]);
            }
        #pragma unroll
        for (int off = 1; off < 16; off <<= 1)
            #pragma unroll
            for (int r = 0; r < 4; ++r)
                mt[r] = fmaxf(mt[r], __shfl_xor(mt[r], off, 64));

        float alpha[4], ps[4];
        #pragma unroll
        for (int r = 0; r < 4; ++r) {
            float mn = fmaxf(m_r[r], mt[r]);
            alpha[r] = __expf(m_r[r] - mn);
            m_r[r] = mn;
            ps[r] = 0.f;
        }
        #pragma unroll
        for (int nt = 0; nt < 4; ++nt)
            #pragma unroll
            for (int r = 0; r < 4; ++r) {
                float p = __expf(s[nt][r] - m_r[r]);
                ps[r] += p;
                Ps[w][lg*4 + r][nt*16 + l15] = f2bf(p);  // C-layout -> row-major P
            }
        #pragma unroll
        for (int off = 1; off < 16; off <<= 1)
            #pragma unroll
            for (int r = 0; r < 4; ++r)
                ps[r] += __shfl_xor(ps[r], off, 64);
        #pragma unroll
        for (int r = 0; r < 4; ++r)
            l_r[r] = l_r[r] * alpha[r] + ps[r];
        #pragma unroll
        for (int dt = 0; dt < 6; ++dt)
            #pragma unroll
            for (int r = 0; r < 4; ++r)
                o[dt][r] *= alpha[r];

        // ---- O += P V  (P from per-wave LDS; same-wave DS ordering) ----
        short8v ap0 = *(const short8v*)&Ps[w][l15][lg*8];
        short8v ap1 = *(const short8v*)&Ps[w][l15][32 + lg*8];
        #pragma unroll
        for (int dt = 0; dt < 6; ++dt) {
            short8v bv0 = *(const short8v*)&Vs[dt*16 + l15][lg*8];
            short8v bv1 = *(const short8v*)&Vs[dt*16 + l15][32 + lg*8];
            o[dt] = __builtin_amdgcn_mfma_f32_16x16x32_bf16(ap0, bv0, o[dt], 0, 0, 0);
            o[dt] = __builtin_amdgcn_mfma_f32_16x16x32_bf16(ap1, bv1, o[dt], 0, 0, 0);
        }
        __syncthreads();
    }

    // ---- epilogue: ctx fp32 (B, LQ, 768) ----
    float* cb = ctx + ((size_t)(bh >> 3) * LQ + qt*64 + w*16) * DM + (bh & 7) * HD;
    #pragma unroll
    for (int r = 0; r < 4; ++r) {
        float inv = 1.f / l_r[r];
        int row = lg*4 + r;
        #pragma unroll
        for (int dt = 0; dt < 6; ++dt)
            cb[(size_t)row * DM + dt*16 + l15] = o[dt][r] * inv;
    }
}

extern "C" void kernel_launch(void* const* d_in, const int* in_sizes, int n_in,
                              void* d_out, int out_size, void* d_ws, size_t ws_size,
                              hipStream_t stream)
{
    const float* query = (const float*)d_in[0];
    const float* key   = (const float*)d_in[1];
    const float* value = (const float*)d_in[2];
    const float* cq    = (const float*)d_in[3];
    const float* ck    = (const float*)d_in[4];
    const float* Wq    = (const float*)d_in[5];
    const float* bqv   = (const float*)d_in[6];
    const float* Wk    = (const float*)d_in[7];
    const float* bkv   = (const float*)d_in[8];
    const float* Wv    = (const float*)d_in[9];
    const float* bvv   = (const float*)d_in[10];
    const float* Wo    = (const float*)d_in[11];
    const float* bov   = (const float*)d_in[12];
    float* out = (float*)d_out;

    ushort* qws = (ushort*)d_ws;                         // B*H*LQ*96 bf16
    ushort* kws = qws + (size_t)BQ * NH * LQ * HD;       // B*H*LK*96 bf16
    ushort* vws = kws + (size_t)BQ * NH * LK * HD;       // B*H*LK*96 bf16
    ushort* vtb = vws + (size_t)BQ * NH * LK * HD;       // B*H*96*LK bf16
    float*  ctx = (float*)(vtb + (size_t)BQ * NH * LK * HD);  // B*LQ*768 fp32
    // total ~94 MB of d_ws

    gemm_rope<1><<<dim3(DM/64, BQ*LQ/64), 256, 0, stream>>>(query, Wq, bqv, cq, qws, LQ);
    gemm_rope<1><<<dim3(DM/64, BQ*LK/64), 256, 0, stream>>>(key,   Wk, bkv, ck, kws, LK);
    gemm_rope<2><<<dim3(DM/64, BQ*LK/64), 256, 0, stream>>>(value, Wv, bvv, nullptr, vws, LK);
    transpose_v<<<dim3(LK/32, HD/32, BQ*NH), 256, 0, stream>>>(vws, vtb);
    attn_mfma<<<dim3(LQ/64, BQ*NH), 256, 0, stream>>>(qws, kws, vtb, ctx);
    gemm_rope<0><<<dim3(DM/64, BQ*LQ/64), 256, 0, stream>>>(ctx, Wo, bov, nullptr, out, LQ);
}

// Round 3
// 407.443 us; speedup vs baseline: 5.3251x; 2.5234x over previous
//
#include <hip/hip_runtime.h>
#include <math.h>

#define DM 768
#define NH 8
#define HD 96
#define BQ 4
#define LQ 1024
#define LK 4096

typedef unsigned short ushort;
typedef unsigned int uint;
typedef __attribute__((ext_vector_type(8))) short short8v;
typedef __attribute__((ext_vector_type(4))) float float4v;

static __device__ __forceinline__ ushort f2bf(float x) {
    union { float f; uint u; } c; c.f = x;
    uint u = c.u;
    u += ((u >> 16) & 1u) + 0x7fffu;   // RNE
    return (ushort)(u >> 16);
}

static __device__ __forceinline__ void gload_lds16(const ushort* g, ushort* l) {
    __builtin_amdgcn_global_load_lds(
        (const __attribute__((address_space(1))) uint*)g,
        (__attribute__((address_space(3))) uint*)l, 16, 0, 0);
}

// fp32 -> bf16, 4 elems/thread, exact grid
__global__ __launch_bounds__(256)
void cvt_bf16(const float* __restrict__ s, ushort* __restrict__ d)
{
    int i = blockIdx.x * 256 + threadIdx.x;
    float4 v = ((const float4*)s)[i];
    uint2 o;
    o.x = (uint)f2bf(v.x) | ((uint)f2bf(v.y) << 16);
    o.y = (uint)f2bf(v.z) | ((uint)f2bf(v.w) << 16);
    ((uint2*)d)[i] = o;
}

// bf16 MFMA GEMM: C[row,j] = sum_d X[row,d]*W[j,d] + bias[j]
// 128x128 tile, BK=64, 4 waves (2x2), wave = 64x64 via 4x4 16x16x32 frags.
// MODE 0: fp32 row-major out. MODE 1: RoPE + bf16 (B,H,L,96). MODE 2: bf16 (B,H,L,96).
template<int MODE>
__global__ __launch_bounds__(256)
void gemm_mfma(const ushort* __restrict__ X, const ushort* __restrict__ Wb,
               const float* __restrict__ bias, const float* __restrict__ coords,
               void* __restrict__ out, int Lshift)
{
    __shared__ ushort As[8192];   // [128][64] bf16, 2-bit XOR swizzled
    __shared__ ushort Bs[8192];

    const int tid  = threadIdx.x;
    const int w    = tid >> 6;
    const int lane = tid & 63;
    const int l15  = lane & 15;
    const int lg   = lane >> 4;
    const int wm   = w >> 1, wn = w & 1;
    const int col0 = blockIdx.x * 128;
    const int row0 = blockIdx.y * 128;

    float4v acc[4][4];
    #pragma unroll
    for (int m = 0; m < 4; ++m)
        #pragma unroll
        for (int n = 0; n < 4; ++n) acc[m][n] = (float4v)0.f;

    // staging geometry (constant over K): issue i=w*4+c writes phys P=i*1024+lane*16
    int Pp[4], rrS[4], cbS[4];
    #pragma unroll
    for (int c = 0; c < 4; ++c) {
        int P = ((w*4 + c) << 10) + lane*16;
        int lgc = P ^ (((P >> 9) & 3) << 5);   // inverse-swizzle: logical byte
        Pp[c]  = P;
        rrS[c] = lgc >> 7;                      // logical row 0..127
        cbS[c] = (lgc & 127) >> 1;              // logical k-elem 0..63
    }
    const ushort* xb = X  + (size_t)row0 * DM;
    const ushort* wb = Wb + (size_t)col0 * DM;

    // fragment read byte offsets (constant over K)
    int offA[2][4], offB[2][4];
    #pragma unroll
    for (int kk = 0; kk < 2; ++kk) {
        #pragma unroll
        for (int m = 0; m < 4; ++m) {
            int byte = (wm*64 + m*16 + l15)*128 + kk*64 + lg*16;
            offA[kk][m] = byte ^ (((byte >> 9) & 3) << 5);
            byte = (wn*64 + m*16 + l15)*128 + kk*64 + lg*16;
            offB[kk][m] = byte ^ (((byte >> 9) & 3) << 5);
        }
    }

    for (int kt = 0; kt < DM; kt += 64) {
        #pragma unroll
        for (int c = 0; c < 4; ++c) {
            gload_lds16(xb + (size_t)rrS[c]*DM + kt + cbS[c], (ushort*)((char*)As + Pp[c]));
            gload_lds16(wb + (size_t)rrS[c]*DM + kt + cbS[c], (ushort*)((char*)Bs + Pp[c]));
        }
        __syncthreads();   // drains vmcnt+lgkm
        #pragma unroll
        for (int kk = 0; kk < 2; ++kk) {
            short8v af[4], bfm[4];
            #pragma unroll
            for (int m = 0; m < 4; ++m)
                af[m] = *(const short8v*)((const char*)As + offA[kk][m]);
            #pragma unroll
            for (int n = 0; n < 4; ++n)
                bfm[n] = *(const short8v*)((const char*)Bs + offB[kk][n]);
            #pragma unroll
            for (int m = 0; m < 4; ++m)
                #pragma unroll
                for (int n = 0; n < 4; ++n)
                    acc[m][n] = __builtin_amdgcn_mfma_f32_16x16x32_bf16(af[m], bfm[n], acc[m][n], 0, 0, 0);
        }
        __syncthreads();
    }

    // ---------------- epilogue ----------------
    const int colbase = col0 + wn*64;
    float bv[4];
    #pragma unroll
    for (int nt = 0; nt < 4; ++nt) bv[nt] = bias[colbase + nt*16 + l15];
    #pragma unroll
    for (int m = 0; m < 4; ++m)
        #pragma unroll
        for (int nt = 0; nt < 4; ++nt)
            #pragma unroll
            for (int r = 0; r < 4; ++r) acc[m][nt][r] += bv[nt];

    if (MODE == 1) {
        const float freq = exp2f(-(float)l15 * 0.83048202372184058696f); // 10000^(-l15/16)
        const int a0 = ((colbase >> 5) + 0) % 3;
        const int a1 = ((colbase >> 5) + 1) % 3;
        const int F  = (colbase >> 4) & 1;   // 1 -> odd nt holds x1 (u<16)
        #pragma unroll
        for (int m = 0; m < 4; ++m) {
            #pragma unroll
            for (int r = 0; r < 4; ++r) {
                int row = row0 + wm*64 + m*16 + lg*4 + r;
                const float* c3 = coords + (size_t)row * 3;
                float sn0, cs0, sn1, cs1;
                __sincosf(c3[a0] * freq, &sn0, &cs0);
                __sincosf(c3[a1] * freq, &sn1, &cs1);
                {
                    float A_ = F ? acc[m][1][r] : acc[m][0][r];
                    float B_ = F ? acc[m][0][r] : acc[m][1][r];
                    float x1 = A_*cs0 - B_*sn0, x2 = A_*sn0 + B_*cs0;
                    if (F) { acc[m][1][r] = x1; acc[m][0][r] = x2; }
                    else   { acc[m][0][r] = x1; acc[m][1][r] = x2; }
                }
                {
                    float A_ = F ? acc[m][3][r] : acc[m][2][r];
                    float B_ = F ? acc[m][2][r] : acc[m][3][r];
                    float x1 = A_*cs1 - B_*sn1, x2 = A_*sn1 + B_*cs1;
                    if (F) { acc[m][3][r] = x1; acc[m][2][r] = x2; }
                    else   { acc[m][2][r] = x1; acc[m][3][r] = x2; }
                }
            }
        }
    }

    if (MODE == 0) {
        float* o32 = (float*)out;
        #pragma unroll
        for (int m = 0; m < 4; ++m)
            #pragma unroll
            for (int r = 0; r < 4; ++r) {
                int row = row0 + wm*64 + m*16 + lg*4 + r;
                #pragma unroll
                for (int nt = 0; nt < 4; ++nt)
                    o32[(size_t)row*DM + colbase + nt*16 + l15] = acc[m][nt][r];
            }
    } else {
        ushort* o16 = (ushort*)out;
        const int Lm1 = (1 << Lshift) - 1;
        int hh[4], tt[4];
        #pragma unroll
        for (int nt = 0; nt < 4; ++nt) {
            int j0 = colbase + nt*16;
            hh[nt] = j0 / HD;
            tt[nt] = j0 % HD + l15;
        }
        #pragma unroll
        for (int m = 0; m < 4; ++m)
            #pragma unroll
            for (int r = 0; r < 4; ++r) {
                int row = row0 + wm*64 + m*16 + lg*4 + r;
                int b = row >> Lshift, l = row & Lm1;
                #pragma unroll
                for (int nt = 0; nt < 4; ++nt)
                    o16[(((size_t)b*NH + hh[nt]) << Lshift | l) * HD + tt[nt]] =
                        f2bf(acc[m][nt][r]);
            }
    }
}

// bf16 (B,H,LK,96) -> bf16 (B,H,96,LK)
__global__ __launch_bounds__(256)
void transpose_v(const ushort* __restrict__ v, ushort* __restrict__ vt)
{
    __shared__ ushort t[32][34];
    const int k0 = blockIdx.x * 32;
    const int d0 = blockIdx.y * 32;
    const size_t ib = (size_t)blockIdx.z * LK * HD;
    const size_t ob = (size_t)blockIdx.z * HD * LK;
    const int c = threadIdx.x & 31, r8 = threadIdx.x >> 5;
    #pragma unroll
    for (int j = 0; j < 4; ++j)
        t[r8 + 8*j][c] = v[ib + (size_t)(k0 + r8 + 8*j) * HD + d0 + c];
    __syncthreads();
    #pragma unroll
    for (int j = 0; j < 4; ++j)
        vt[ob + (size_t)(d0 + r8 + 8*j) * LK + k0 + c] = t[c][r8 + 8*j];
}

// MFMA flash attention. Block = 4 waves x 64 q-rows; wave owns 16 rows. KV tiles of 64.
__global__ __launch_bounds__(256)
void attn_mfma(const ushort* __restrict__ q, const ushort* __restrict__ k,
               const ushort* __restrict__ vt, ushort* __restrict__ ctx)
{
    __shared__ ushort Ks[64][104];
    __shared__ ushort Vs[96][72];
    __shared__ ushort Ps[4][16][72];

    const int tid  = threadIdx.x;
    const int w    = tid >> 6;
    const int lane = tid & 63;
    const int l15  = lane & 15;
    const int lg   = lane >> 4;

    const int qt = blockIdx.x;
    const int bh = blockIdx.y;

    const ushort* qg = q  + (((size_t)bh * LQ + qt*64 + w*16 + l15) * HD);
    const ushort* kg = k  + (size_t)bh * LK * HD;
    const ushort* vg = vt + (size_t)bh * HD * LK;

    short8v aq[3];
    #pragma unroll
    for (int dc = 0; dc < 3; ++dc)
        aq[dc] = *(const short8v*)(qg + dc*32 + lg*8);

    float4v o[6];
    float m_r[4], l_r[4];
    #pragma unroll
    for (int dt = 0; dt < 6; ++dt) o[dt] = (float4v)0.f;
    #pragma unroll
    for (int r = 0; r < 4; ++r) { m_r[r] = -1e30f; l_r[r] = 0.f; }

    const float scale = 0.10206207261596575f;  // 1/sqrt(96)

    for (int kt = 0; kt < LK; kt += 64) {
        #pragma unroll
        for (int j = 0; j < 3; ++j) {
            int c = tid + 256*j;
            int key = c / 12, d8 = c % 12;
            *(short8v*)&Ks[key][d8*8] =
                *(const short8v*)(kg + (size_t)(kt + key) * HD + d8*8);
        }
        #pragma unroll
        for (int j = 0; j < 3; ++j) {
            int c = tid + 256*j;
            int d = c >> 3, k8 = c & 7;
            *(short8v*)&Vs[d][k8*8] =
                *(const short8v*)(vg + (size_t)d * LK + kt + k8*8);
        }
        __syncthreads();

        float4v s[4];
        #pragma unroll
        for (int nt = 0; nt < 4; ++nt) {
            s[nt] = (float4v)0.f;
            #pragma unroll
            for (int dc = 0; dc < 3; ++dc) {
                short8v bk = *(const short8v*)&Ks[nt*16 + l15][dc*32 + lg*8];
                s[nt] = __builtin_amdgcn_mfma_f32_16x16x32_bf16(aq[dc], bk, s[nt], 0, 0, 0);
            }
        }

        float mt[4];
        #pragma unroll
        for (int r = 0; r < 4; ++r) mt[r] = -1e30f;
        #pragma unroll
        for (int nt = 0; nt < 4; ++nt)
            #pragma unroll
            for (int r = 0; r < 4; ++r) {
                s[nt][r] *= scale;
                mt[r] = fmaxf(mt[r], s[nt][r]);
            }
        #pragma unroll
        for (int off = 1; off < 16; off <<= 1)
            #pragma unroll
            for (int r = 0; r < 4; ++r)
                mt[r] = fmaxf(mt[r], __shfl_xor(mt[r], off, 64));

        float alpha[4], ps[4];
        #pragma unroll
        for (int r = 0; r < 4; ++r) {
            float mn = fmaxf(m_r[r], mt[r]);
            alpha[r] = __expf(m_r[r] - mn);
            m_r[r] = mn;
            ps[r] = 0.f;
        }
        #pragma unroll
        for (int nt = 0; nt < 4; ++nt)
            #pragma unroll
            for (int r = 0; r < 4; ++r) {
                float p = __expf(s[nt][r] - m_r[r]);
                ps[r] += p;
                Ps[w][lg*4 + r][nt*16 + l15] = f2bf(p);
            }
        #pragma unroll
        for (int off = 1; off < 16; off <<= 1)
            #pragma unroll
            for (int r = 0; r < 4; ++r)
                ps[r] += __shfl_xor(ps[r], off, 64);
        #pragma unroll
        for (int r = 0; r < 4; ++r)
            l_r[r] = l_r[r] * alpha[r] + ps[r];
        #pragma unroll
        for (int dt = 0; dt < 6; ++dt)
            #pragma unroll
            for (int r = 0; r < 4; ++r)
                o[dt][r] *= alpha[r];

        short8v ap0 = *(const short8v*)&Ps[w][l15][lg*8];
        short8v ap1 = *(const short8v*)&Ps[w][l15][32 + lg*8];
        #pragma unroll
        for (int dt = 0; dt < 6; ++dt) {
            short8v bv0 = *(const short8v*)&Vs[dt*16 + l15][lg*8];
            short8v bv1 = *(const short8v*)&Vs[dt*16 + l15][32 + lg*8];
            o[dt] = __builtin_amdgcn_mfma_f32_16x16x32_bf16(ap0, bv0, o[dt], 0, 0, 0);
            o[dt] = __builtin_amdgcn_mfma_f32_16x16x32_bf16(ap1, bv1, o[dt], 0, 0, 0);
        }
        __syncthreads();
    }

    ushort* cb = ctx + ((size_t)(bh >> 3) * LQ + qt*64 + w*16) * DM + (bh & 7) * HD;
    #pragma unroll
    for (int r = 0; r < 4; ++r) {
        float inv = 1.f / l_r[r];
        int row = lg*4 + r;
        #pragma unroll
        for (int dt = 0; dt < 6; ++dt)
            cb[(size_t)row * DM + dt*16 + l15] = f2bf(o[dt][r] * inv);
    }
}

extern "C" void kernel_launch(void* const* d_in, const int* in_sizes, int n_in,
                              void* d_out, int out_size, void* d_ws, size_t ws_size,
                              hipStream_t stream)
{
    const float* query = (const float*)d_in[0];
    const float* key   = (const float*)d_in[1];
    const float* value = (const float*)d_in[2];
    const float* cq    = (const float*)d_in[3];
    const float* ck    = (const float*)d_in[4];
    const float* Wq    = (const float*)d_in[5];
    const float* bqv   = (const float*)d_in[6];
    const float* Wk    = (const float*)d_in[7];
    const float* bkv   = (const float*)d_in[8];
    const float* Wv    = (const float*)d_in[9];
    const float* bvv   = (const float*)d_in[10];
    const float* Wo    = (const float*)d_in[11];
    const float* bov   = (const float*)d_in[12];
    float* out = (float*)d_out;

    const size_t NQ = (size_t)BQ * LQ * DM;   // 3,145,728
    const size_t NK = (size_t)BQ * LK * DM;   // 12,582,912
    const size_t NW = (size_t)DM * DM;        //    589,824

    ushort* qx  = (ushort*)d_ws;        // bf16 query input
    ushort* kx  = qx  + NQ;             // bf16 key input   (later reused as vt)
    ushort* vx  = kx  + NK;             // bf16 value input
    ushort* wq  = vx  + NK;
    ushort* wk  = wq  + NW;
    ushort* wv  = wk  + NW;
    ushort* wo  = wv  + NW;
    ushort* qws = wo  + NW;             // q (B,H,LQ,96)
    ushort* kws = qws + NQ;             // k (B,H,LK,96)
    ushort* vws = kws + NK;             // v (B,H,LK,96)
    ushort* vtb = kx;                   // vt (B,H,96,LK) — overlays kx (dead after gemm_k)
    ushort* ctx = qx;                   // ctx (B,LQ,768) — overlays qx (dead after gemm_q)
    // high-water: ~118 MB

    cvt_bf16<<<(int)(NQ/4/256), 256, 0, stream>>>(query, qx);
    cvt_bf16<<<(int)(NK/4/256), 256, 0, stream>>>(key,   kx);
    cvt_bf16<<<(int)(NK/4/256), 256, 0, stream>>>(value, vx);
    cvt_bf16<<<(int)(NW/4/256), 256, 0, stream>>>(Wq, wq);
    cvt_bf16<<<(int)(NW/4/256), 256, 0, stream>>>(Wk, wk);
    cvt_bf16<<<(int)(NW/4/256), 256, 0, stream>>>(Wv, wv);
    cvt_bf16<<<(int)(NW/4/256), 256, 0, stream>>>(Wo, wo);

    gemm_mfma<1><<<dim3(DM/128, BQ*LQ/128), 256, 0, stream>>>(qx, wq, bqv, cq, qws, 10);
    gemm_mfma<1><<<dim3(DM/128, BQ*LK/128), 256, 0, stream>>>(kx, wk, bkv, ck, kws, 12);
    gemm_mfma<2><<<dim3(DM/128, BQ*LK/128), 256, 0, stream>>>(vx, wv, bvv, nullptr, vws, 12);
    transpose_v<<<dim3(LK/32, HD/32, BQ*NH), 256, 0, stream>>>(vws, vtb);
    attn_mfma<<<dim3(LQ/64, BQ*NH), 256, 0, stream>>>(qws, kws, vtb, ctx);
    gemm_mfma<0><<<dim3(DM/128, BQ*LQ/128), 256, 0, stream>>>(ctx, wo, bov, nullptr, out, 0);
}

// Round 4
// 313.902 us; speedup vs baseline: 6.9120x; 1.2980x over previous
//
#include <hip/hip_runtime.h>
#include <math.h>

#define DM 768
#define NH 8
#define HD 96
#define BQ 4
#define LQ 1024
#define LK 4096
#define BH (BQ*NH)
#define KVS 2              // kv-split factor
#define KC (LK/KVS)        // keys per chunk
#define NT (KC/64)         // 64-key tiles per block

typedef unsigned short ushort;
typedef unsigned int uint;
typedef __attribute__((ext_vector_type(8))) short short8v;
typedef __attribute__((ext_vector_type(4))) float float4v;

static __device__ __forceinline__ ushort f2bf(float x) {
    union { float f; uint u; } c; c.f = x;
    uint u = c.u;
    u += ((u >> 16) & 1u) + 0x7fffu;   // RNE
    return (ushort)(u >> 16);
}

static __device__ __forceinline__ void gload_lds16(const ushort* g, ushort* l) {
    __builtin_amdgcn_global_load_lds(
        (const __attribute__((address_space(1))) uint*)g,
        (__attribute__((address_space(3))) uint*)l, 16, 0, 0);
}

// fp32 -> bf16, 4 elems/thread
__global__ __launch_bounds__(256)
void cvt_bf16(const float* __restrict__ s, ushort* __restrict__ d)
{
    int i = blockIdx.x * 256 + threadIdx.x;
    float4 v = ((const float4*)s)[i];
    uint2 o;
    o.x = (uint)f2bf(v.x) | ((uint)f2bf(v.y) << 16);
    o.y = (uint)f2bf(v.z) | ((uint)f2bf(v.w) << 16);
    ((uint2*)d)[i] = o;
}

// bf16 MFMA GEMM (unchanged from R3): C = X @ W^T + b, 128x128xBK64
template<int MODE>
__global__ __launch_bounds__(256)
void gemm_mfma(const ushort* __restrict__ X, const ushort* __restrict__ Wb,
               const float* __restrict__ bias, const float* __restrict__ coords,
               void* __restrict__ out, int Lshift)
{
    __shared__ ushort As[8192];
    __shared__ ushort Bs[8192];

    const int tid  = threadIdx.x;
    const int w    = tid >> 6;
    const int lane = tid & 63;
    const int l15  = lane & 15;
    const int lg   = lane >> 4;
    const int wm   = w >> 1, wn = w & 1;
    const int col0 = blockIdx.x * 128;
    const int row0 = blockIdx.y * 128;

    float4v acc[4][4];
    #pragma unroll
    for (int m = 0; m < 4; ++m)
        #pragma unroll
        for (int n = 0; n < 4; ++n) acc[m][n] = (float4v)0.f;

    int Pp[4], rrS[4], cbS[4];
    #pragma unroll
    for (int c = 0; c < 4; ++c) {
        int P = ((w*4 + c) << 10) + lane*16;
        int lgc = P ^ (((P >> 9) & 3) << 5);
        Pp[c]  = P;
        rrS[c] = lgc >> 7;
        cbS[c] = (lgc & 127) >> 1;
    }
    const ushort* xb = X  + (size_t)row0 * DM;
    const ushort* wb = Wb + (size_t)col0 * DM;

    int offA[2][4], offB[2][4];
    #pragma unroll
    for (int kk = 0; kk < 2; ++kk) {
        #pragma unroll
        for (int m = 0; m < 4; ++m) {
            int byte = (wm*64 + m*16 + l15)*128 + kk*64 + lg*16;
            offA[kk][m] = byte ^ (((byte >> 9) & 3) << 5);
            byte = (wn*64 + m*16 + l15)*128 + kk*64 + lg*16;
            offB[kk][m] = byte ^ (((byte >> 9) & 3) << 5);
        }
    }

    for (int kt = 0; kt < DM; kt += 64) {
        #pragma unroll
        for (int c = 0; c < 4; ++c) {
            gload_lds16(xb + (size_t)rrS[c]*DM + kt + cbS[c], (ushort*)((char*)As + Pp[c]));
            gload_lds16(wb + (size_t)rrS[c]*DM + kt + cbS[c], (ushort*)((char*)Bs + Pp[c]));
        }
        __syncthreads();
        #pragma unroll
        for (int kk = 0; kk < 2; ++kk) {
            short8v af[4], bfm[4];
            #pragma unroll
            for (int m = 0; m < 4; ++m)
                af[m] = *(const short8v*)((const char*)As + offA[kk][m]);
            #pragma unroll
            for (int n = 0; n < 4; ++n)
                bfm[n] = *(const short8v*)((const char*)Bs + offB[kk][n]);
            #pragma unroll
            for (int m = 0; m < 4; ++m)
                #pragma unroll
                for (int n = 0; n < 4; ++n)
                    acc[m][n] = __builtin_amdgcn_mfma_f32_16x16x32_bf16(af[m], bfm[n], acc[m][n], 0, 0, 0);
        }
        __syncthreads();
    }

    const int colbase = col0 + wn*64;
    float bv[4];
    #pragma unroll
    for (int nt = 0; nt < 4; ++nt) bv[nt] = bias[colbase + nt*16 + l15];
    #pragma unroll
    for (int m = 0; m < 4; ++m)
        #pragma unroll
        for (int nt = 0; nt < 4; ++nt)
            #pragma unroll
            for (int r = 0; r < 4; ++r) acc[m][nt][r] += bv[nt];

    if (MODE == 1) {
        const float freq = exp2f(-(float)l15 * 0.83048202372184058696f);
        const int a0 = ((colbase >> 5) + 0) % 3;
        const int a1 = ((colbase >> 5) + 1) % 3;
        const int F  = (colbase >> 4) & 1;
        #pragma unroll
        for (int m = 0; m < 4; ++m) {
            #pragma unroll
            for (int r = 0; r < 4; ++r) {
                int row = row0 + wm*64 + m*16 + lg*4 + r;
                const float* c3 = coords + (size_t)row * 3;
                float sn0, cs0, sn1, cs1;
                __sincosf(c3[a0] * freq, &sn0, &cs0);
                __sincosf(c3[a1] * freq, &sn1, &cs1);
                {
                    float A_ = F ? acc[m][1][r] : acc[m][0][r];
                    float B_ = F ? acc[m][0][r] : acc[m][1][r];
                    float x1 = A_*cs0 - B_*sn0, x2 = A_*sn0 + B_*cs0;
                    if (F) { acc[m][1][r] = x1; acc[m][0][r] = x2; }
                    else   { acc[m][0][r] = x1; acc[m][1][r] = x2; }
                }
                {
                    float A_ = F ? acc[m][3][r] : acc[m][2][r];
                    float B_ = F ? acc[m][2][r] : acc[m][3][r];
                    float x1 = A_*cs1 - B_*sn1, x2 = A_*sn1 + B_*cs1;
                    if (F) { acc[m][3][r] = x1; acc[m][2][r] = x2; }
                    else   { acc[m][2][r] = x1; acc[m][3][r] = x2; }
                }
            }
        }
    }

    if (MODE == 0) {
        float* o32 = (float*)out;
        #pragma unroll
        for (int m = 0; m < 4; ++m)
            #pragma unroll
            for (int r = 0; r < 4; ++r) {
                int row = row0 + wm*64 + m*16 + lg*4 + r;
                #pragma unroll
                for (int nt = 0; nt < 4; ++nt)
                    o32[(size_t)row*DM + colbase + nt*16 + l15] = acc[m][nt][r];
            }
    } else {
        ushort* o16 = (ushort*)out;
        const int Lm1 = (1 << Lshift) - 1;
        int hh[4], tt[4];
        #pragma unroll
        for (int nt = 0; nt < 4; ++nt) {
            int j0 = colbase + nt*16;
            hh[nt] = j0 / HD;
            tt[nt] = j0 % HD + l15;
        }
        #pragma unroll
        for (int m = 0; m < 4; ++m)
            #pragma unroll
            for (int r = 0; r < 4; ++r) {
                int row = row0 + wm*64 + m*16 + lg*4 + r;
                int b = row >> Lshift, l = row & Lm1;
                #pragma unroll
                for (int nt = 0; nt < 4; ++nt)
                    o16[(((size_t)b*NH + hh[nt]) << Lshift | l) * HD + tt[nt]] =
                        f2bf(acc[m][nt][r]);
            }
    }
}

// bf16 (B,H,LK,96) -> bf16 (B,H,96,LK)
__global__ __launch_bounds__(256)
void transpose_v(const ushort* __restrict__ v, ushort* __restrict__ vt)
{
    __shared__ ushort t[32][34];
    const int k0 = blockIdx.x * 32;
    const int d0 = blockIdx.y * 32;
    const size_t ib = (size_t)blockIdx.z * LK * HD;
    const size_t ob = (size_t)blockIdx.z * HD * LK;
    const int c = threadIdx.x & 31, r8 = threadIdx.x >> 5;
    #pragma unroll
    for (int j = 0; j < 4; ++j)
        t[r8 + 8*j][c] = v[ib + (size_t)(k0 + r8 + 8*j) * HD + d0 + c];
    __syncthreads();
    #pragma unroll
    for (int j = 0; j < 4; ++j)
        vt[ob + (size_t)(d0 + r8 + 8*j) * LK + k0 + c] = t[c][r8 + 8*j];
}

// MFMA flash attention, KV-split. Block = 4 waves x 64 q-rows; KVBLK=64.
// Reg-staged async prefetch; XOR-swizzled K [64][128] / V [96][64] LDS.
// Writes unnormalized partial O (fp32) + per-row m,l.
__global__ __launch_bounds__(256, 4)
void attn_mfma(const ushort* __restrict__ q, const ushort* __restrict__ k,
               const ushort* __restrict__ vt, float* __restrict__ op,
               float* __restrict__ mlb)
{
    __shared__ ushort Ks[64*128];    // 16 KB, padded rows, slot^=(row&7)
    __shared__ ushort Vs[96*64];     // 12 KB, slot^=(row&7)
    __shared__ ushort Ps[4][16][72]; // 9 KB

    const int tid  = threadIdx.x;
    const int w    = tid >> 6;
    const int lane = tid & 63;
    const int l15  = lane & 15;
    const int lg   = lane >> 4;

    const int qt = blockIdx.x;
    const int bh = blockIdx.y;
    const int sc = blockIdx.z;

    const ushort* qg = q  + ((size_t)bh * LQ + qt*64 + w*16 + l15) * HD;
    const ushort* kg = k  + ((size_t)bh * LK + (size_t)sc * KC) * HD;
    const ushort* vg = vt + (size_t)bh * HD * LK + (size_t)sc * KC;

    short8v aq[3];
    #pragma unroll
    for (int dc = 0; dc < 3; ++dc)
        aq[dc] = *(const short8v*)(qg + dc*32 + lg*8);

    // staging geometry (constant)
    int kdst[3], ksrc[3], vdst[3], vsrc[3];
    #pragma unroll
    for (int j = 0; j < 3; ++j) {
        int c = tid + 256*j;
        int kr = c / 12, ks = c % 12;
        kdst[j] = kr*256 + ((ks ^ (kr & 7)) << 4);
        ksrc[j] = kr*HD + ks*8;
        int vr = c >> 3, vs = c & 7;
        vdst[j] = vr*128 + ((vs ^ (vr & 7)) << 4);
        vsrc[j] = vr*LK + vs*8;
    }
    // fragment-read swizzle terms (constant)
    int tK[3], tV[2];
    #pragma unroll
    for (int dc = 0; dc < 3; ++dc) tK[dc] = ((dc*4 + lg) ^ (l15 & 7)) << 4;
    #pragma unroll
    for (int h2 = 0; h2 < 2; ++h2)  tV[h2] = ((h2*4 + lg) ^ (l15 & 7)) << 4;

    float4v o[6];
    float m_r[4], l_r[4];
    #pragma unroll
    for (int dt = 0; dt < 6; ++dt) o[dt] = (float4v)0.f;
    #pragma unroll
    for (int r = 0; r < 4; ++r) { m_r[r] = -1e30f; l_r[r] = 0.f; }

    const float scale = 0.10206207261596575f;  // 1/sqrt(96)

    short8v kreg[3], vreg[3];
    #pragma unroll
    for (int j = 0; j < 3; ++j) {
        kreg[j] = *(const short8v*)(kg + ksrc[j]);
        vreg[j] = *(const short8v*)(vg + vsrc[j]);
    }
    #pragma unroll
    for (int j = 0; j < 3; ++j) {
        *(short8v*)((char*)Ks + kdst[j]) = kreg[j];
        *(short8v*)((char*)Vs + vdst[j]) = vreg[j];
    }
    __syncthreads();

    for (int t = 0; t < NT; ++t) {
        // issue next tile's loads early (latency hides under compute)
        if (t + 1 < NT) {
            const ushort* kn = kg + (size_t)(t+1)*64*HD;
            const ushort* vn = vg + (t+1)*64;
            #pragma unroll
            for (int j = 0; j < 3; ++j) {
                kreg[j] = *(const short8v*)(kn + ksrc[j]);
                vreg[j] = *(const short8v*)(vn + vsrc[j]);
            }
        }

        // ---- S = Q K^T ----
        float4v s[4];
        #pragma unroll
        for (int nt = 0; nt < 4; ++nt) {
            s[nt] = (float4v)0.f;
            #pragma unroll
            for (int dc = 0; dc < 3; ++dc) {
                short8v bk = *(const short8v*)((const char*)Ks + nt*4096 + l15*256 + tK[dc]);
                s[nt] = __builtin_amdgcn_mfma_f32_16x16x32_bf16(aq[dc], bk, s[nt], 0, 0, 0);
            }
        }

        // ---- online softmax ----
        float mt[4];
        #pragma unroll
        for (int r = 0; r < 4; ++r) mt[r] = -1e30f;
        #pragma unroll
        for (int nt = 0; nt < 4; ++nt)
            #pragma unroll
            for (int r = 0; r < 4; ++r) {
                s[nt][r] *= scale;
                mt[r] = fmaxf(mt[r], s[nt][r]);
            }
        #pragma unroll
        for (int off = 1; off < 16; off <<= 1)
            #pragma unroll
            for (int r = 0; r < 4; ++r)
                mt[r] = fmaxf(mt[r], __shfl_xor(mt[r], off, 64));

        float alpha[4], ps[4];
        #pragma unroll
        for (int r = 0; r < 4; ++r) {
            float mn = fmaxf(m_r[r], mt[r]);
            alpha[r] = __expf(m_r[r] - mn);
            m_r[r] = mn;
            ps[r] = 0.f;
        }
        #pragma unroll
        for (int nt = 0; nt < 4; ++nt)
            #pragma unroll
            for (int r = 0; r < 4; ++r) {
                float p = __expf(s[nt][r] - m_r[r]);
                ps[r] += p;
                Ps[w][lg*4 + r][nt*16 + l15] = f2bf(p);
            }
        #pragma unroll
        for (int off = 1; off < 16; off <<= 1)
            #pragma unroll
            for (int r = 0; r < 4; ++r)
                ps[r] += __shfl_xor(ps[r], off, 64);
        #pragma unroll
        for (int r = 0; r < 4; ++r)
            l_r[r] = l_r[r] * alpha[r] + ps[r];
        #pragma unroll
        for (int dt = 0; dt < 6; ++dt)
            #pragma unroll
            for (int r = 0; r < 4; ++r)
                o[dt][r] *= alpha[r];

        // ---- O += P V  (P same-wave LDS roundtrip) ----
        short8v ap0 = *(const short8v*)&Ps[w][l15][lg*8];
        short8v ap1 = *(const short8v*)&Ps[w][l15][32 + lg*8];
        #pragma unroll
        for (int dt = 0; dt < 6; ++dt) {
            short8v bv0 = *(const short8v*)((const char*)Vs + dt*2048 + l15*128 + tV[0]);
            short8v bv1 = *(const short8v*)((const char*)Vs + dt*2048 + l15*128 + tV[1]);
            o[dt] = __builtin_amdgcn_mfma_f32_16x16x32_bf16(ap0, bv0, o[dt], 0, 0, 0);
            o[dt] = __builtin_amdgcn_mfma_f32_16x16x32_bf16(ap1, bv1, o[dt], 0, 0, 0);
        }
        __syncthreads();          // everyone done reading Ks/Vs

        if (t + 1 < NT) {
            #pragma unroll
            for (int j = 0; j < 3; ++j) {
                *(short8v*)((char*)Ks + kdst[j]) = kreg[j];
                *(short8v*)((char*)Vs + vdst[j]) = vreg[j];
            }
        }
        __syncthreads();          // next tile visible
    }

    // ---- epilogue: unnormalized partials ----
    float* ob = op + (((size_t)sc * BH + bh) * LQ + qt*64 + w*16) * HD;
    #pragma unroll
    for (int r = 0; r < 4; ++r) {
        int row = lg*4 + r;
        #pragma unroll
        for (int dt = 0; dt < 6; ++dt)
            ob[(size_t)row * HD + dt*16 + l15] = o[dt][r];
    }
    if (l15 == 0) {
        size_t mlrow = ((size_t)sc * BH + bh) * LQ + qt*64 + w*16 + lg*4;
        #pragma unroll
        for (int r = 0; r < 4; ++r) {
            mlb[(mlrow + r)*2 + 0] = m_r[r];
            mlb[(mlrow + r)*2 + 1] = l_r[r];
        }
    }
}

// merge KVS=2 partials -> ctx bf16 (B, LQ, 768)
__global__ __launch_bounds__(256)
void combine(const float* __restrict__ op, const float* __restrict__ mlb,
             ushort* __restrict__ ctx)
{
    const int NROW = BH * LQ;
    int idx = blockIdx.x * 256 + threadIdx.x;   // NROW*12 total
    int row = idx / 12, seg = idx % 12;
    float m0 = mlb[(size_t)row*2],          l0 = mlb[(size_t)row*2 + 1];
    float m1 = mlb[(size_t)(NROW + row)*2], l1 = mlb[(size_t)(NROW + row)*2 + 1];
    float ms = fmaxf(m0, m1);
    float w0 = __expf(m0 - ms), w1 = __expf(m1 - ms);
    float inv = 1.f / (l0*w0 + l1*w1);
    const float4* p0 = (const float4*)(op + (size_t)row*HD + seg*8);
    const float4* p1 = (const float4*)(op + (size_t)(NROW + row)*HD + seg*8);
    float4 a0 = p0[0], a1 = p0[1];
    float4 b0 = p1[0], b1 = p1[1];
    float r0 = (a0.x*w0 + b0.x*w1)*inv, r1 = (a0.y*w0 + b0.y*w1)*inv;
    float r2 = (a0.z*w0 + b0.z*w1)*inv, r3 = (a0.w*w0 + b0.w*w1)*inv;
    float r4 = (a1.x*w0 + b1.x*w1)*inv, r5 = (a1.y*w0 + b1.y*w1)*inv;
    float r6 = (a1.z*w0 + b1.z*w1)*inv, r7 = (a1.w*w0 + b1.w*w1)*inv;
    int bh = row / LQ, l = row % LQ;
    int b = bh >> 3, h = bh & 7;
    ushort* o = ctx + ((size_t)b * LQ + l) * DM + h * HD + seg*8;
    uint4 pk;
    pk.x = (uint)f2bf(r0) | ((uint)f2bf(r1) << 16);
    pk.y = (uint)f2bf(r2) | ((uint)f2bf(r3) << 16);
    pk.z = (uint)f2bf(r4) | ((uint)f2bf(r5) << 16);
    pk.w = (uint)f2bf(r6) | ((uint)f2bf(r7) << 16);
    *(uint4*)o = pk;
}

extern "C" void kernel_launch(void* const* d_in, const int* in_sizes, int n_in,
                              void* d_out, int out_size, void* d_ws, size_t ws_size,
                              hipStream_t stream)
{
    const float* query = (const float*)d_in[0];
    const float* key   = (const float*)d_in[1];
    const float* value = (const float*)d_in[2];
    const float* cq    = (const float*)d_in[3];
    const float* ck    = (const float*)d_in[4];
    const float* Wq    = (const float*)d_in[5];
    const float* bqv   = (const float*)d_in[6];
    const float* Wk    = (const float*)d_in[7];
    const float* bkv   = (const float*)d_in[8];
    const float* Wv    = (const float*)d_in[9];
    const float* bvv   = (const float*)d_in[10];
    const float* Wo    = (const float*)d_in[11];
    const float* bov   = (const float*)d_in[12];
    float* out = (float*)d_out;

    const size_t NQ = (size_t)BQ * LQ * DM;
    const size_t NK = (size_t)BQ * LK * DM;
    const size_t NW = (size_t)DM * DM;

    ushort* qx  = (ushort*)d_ws;
    ushort* kx  = qx  + NQ;
    ushort* vx  = kx  + NK;
    ushort* wq  = vx  + NK;
    ushort* wk  = wq  + NW;
    ushort* wv  = wk  + NW;
    ushort* wo  = wv  + NW;
    ushort* qws = wo  + NW;
    ushort* kws = qws + NQ;
    ushort* vws = kws + NK;
    ushort* vtb = kx;                 // overlays kx (dead after gemm_k)
    ushort* ctx = qx;                 // overlays qx (dead after gemm_q)
    float*  op  = (float*)vws;        // overlays vws (dead after transpose_v): 6.3M f
    float*  mlb = (float*)vx;         // overlays vx (dead after gemm_v): 131K f

    cvt_bf16<<<(int)(NQ/4/256), 256, 0, stream>>>(query, qx);
    cvt_bf16<<<(int)(NK/4/256), 256, 0, stream>>>(key,   kx);
    cvt_bf16<<<(int)(NK/4/256), 256, 0, stream>>>(value, vx);
    cvt_bf16<<<(int)(NW/4/256), 256, 0, stream>>>(Wq, wq);
    cvt_bf16<<<(int)(NW/4/256), 256, 0, stream>>>(Wk, wk);
    cvt_bf16<<<(int)(NW/4/256), 256, 0, stream>>>(Wv, wv);
    cvt_bf16<<<(int)(NW/4/256), 256, 0, stream>>>(Wo, wo);

    gemm_mfma<1><<<dim3(DM/128, BQ*LQ/128), 256, 0, stream>>>(qx, wq, bqv, cq, qws, 10);
    gemm_mfma<1><<<dim3(DM/128, BQ*LK/128), 256, 0, stream>>>(kx, wk, bkv, ck, kws, 12);
    gemm_mfma<2><<<dim3(DM/128, BQ*LK/128), 256, 0, stream>>>(vx, wv, bvv, nullptr, vws, 12);
    transpose_v<<<dim3(LK/32, HD/32, BQ*NH), 256, 0, stream>>>(vws, vtb);
    attn_mfma<<<dim3(LQ/64, BH, KVS), 256, 0, stream>>>(qws, kws, vtb, op, mlb);
    combine<<<BH*LQ*12/256, 256, 0, stream>>>(op, mlb, ctx);
    gemm_mfma<0><<<dim3(DM/128, BQ*LQ/128), 256, 0, stream>>>(ctx, wo, bov, nullptr, out, 0);
}

// Round 5
// 262.232 us; speedup vs baseline: 8.2739x; 1.1970x over previous
//
#include <hip/hip_runtime.h>
#include <math.h>

#define DM 768
#define NH 8
#define HD 96
#define BQ 4
#define LQ 1024
#define LK 4096
#define BH (BQ*NH)
#define KVS 2              // kv-split factor
#define KC (LK/KVS)        // keys per chunk
#define NT (KC/64)         // 64-key tiles per block

typedef unsigned short ushort;
typedef unsigned int uint;
typedef __attribute__((ext_vector_type(8))) short short8v;
typedef __attribute__((ext_vector_type(4))) float float4v;

static __device__ __forceinline__ ushort f2bf(float x) {
    union { float f; uint u; } c; c.f = x;
    uint u = c.u;
    u += ((u >> 16) & 1u) + 0x7fffu;   // RNE
    return (ushort)(u >> 16);
}

static __device__ __forceinline__ uint cvtpk(float lo, float hi) {
    uint d;
    asm("v_cvt_pk_bf16_f32 %0, %1, %2" : "=v"(d) : "v"(lo), "v"(hi));
    return d;
}

static __device__ __forceinline__ void gload_lds16(const ushort* g, ushort* l) {
    __builtin_amdgcn_global_load_lds(
        (const __attribute__((address_space(1))) uint*)g,
        (__attribute__((address_space(3))) uint*)l, 16, 0, 0);
}

// fp32 -> bf16, 4 elems/thread
__global__ __launch_bounds__(256)
void cvt_bf16(const float* __restrict__ s, ushort* __restrict__ d)
{
    int i = blockIdx.x * 256 + threadIdx.x;
    float4 v = ((const float4*)s)[i];
    uint2 o;
    o.x = (uint)f2bf(v.x) | ((uint)f2bf(v.y) << 16);
    o.y = (uint)f2bf(v.z) | ((uint)f2bf(v.w) << 16);
    ((uint2*)d)[i] = o;
}

// bf16 MFMA GEMM: C = X @ W^T + b, 128x128xBK64.
// MODE 0: fp32 row-major. MODE 1: RoPE + bf16 (B,H,L,96). MODE 2: bf16 (B,H,L,96).
// MODE 3: bf16 V^T (B,H,96,LK) via LDS re-transpose of the C tile.
template<int MODE>
__global__ __launch_bounds__(256)
void gemm_mfma(const ushort* __restrict__ X, const ushort* __restrict__ Wb,
               const float* __restrict__ bias, const float* __restrict__ coords,
               void* __restrict__ out, int Lshift)
{
    __shared__ ushort Sh[16384];     // As = Sh[0:8192], Bs = Sh[8192:16384]
    ushort* As = Sh;
    ushort* Bs = Sh + 8192;

    const int tid  = threadIdx.x;
    const int w    = tid >> 6;
    const int lane = tid & 63;
    const int l15  = lane & 15;
    const int lg   = lane >> 4;
    const int wm   = w >> 1, wn = w & 1;
    const int col0 = blockIdx.x * 128;
    const int row0 = blockIdx.y * 128;

    float4v acc[4][4];
    #pragma unroll
    for (int m = 0; m < 4; ++m)
        #pragma unroll
        for (int n = 0; n < 4; ++n) acc[m][n] = (float4v)0.f;

    int Pp[4], rrS[4], cbS[4];
    #pragma unroll
    for (int c = 0; c < 4; ++c) {
        int P = ((w*4 + c) << 10) + lane*16;
        int lgc = P ^ (((P >> 9) & 3) << 5);
        Pp[c]  = P;
        rrS[c] = lgc >> 7;
        cbS[c] = (lgc & 127) >> 1;
    }
    const ushort* xb = X  + (size_t)row0 * DM;
    const ushort* wb = Wb + (size_t)col0 * DM;

    int offA[2][4], offB[2][4];
    #pragma unroll
    for (int kk = 0; kk < 2; ++kk) {
        #pragma unroll
        for (int m = 0; m < 4; ++m) {
            int byte = (wm*64 + m*16 + l15)*128 + kk*64 + lg*16;
            offA[kk][m] = byte ^ (((byte >> 9) & 3) << 5);
            byte = (wn*64 + m*16 + l15)*128 + kk*64 + lg*16;
            offB[kk][m] = byte ^ (((byte >> 9) & 3) << 5);
        }
    }

    for (int kt = 0; kt < DM; kt += 64) {
        #pragma unroll
        for (int c = 0; c < 4; ++c) {
            gload_lds16(xb + (size_t)rrS[c]*DM + kt + cbS[c], (ushort*)((char*)As + Pp[c]));
            gload_lds16(wb + (size_t)rrS[c]*DM + kt + cbS[c], (ushort*)((char*)Bs + Pp[c]));
        }
        __syncthreads();
        #pragma unroll
        for (int kk = 0; kk < 2; ++kk) {
            short8v af[4], bfm[4];
            #pragma unroll
            for (int m = 0; m < 4; ++m)
                af[m] = *(const short8v*)((const char*)As + offA[kk][m]);
            #pragma unroll
            for (int n = 0; n < 4; ++n)
                bfm[n] = *(const short8v*)((const char*)Bs + offB[kk][n]);
            #pragma unroll
            for (int m = 0; m < 4; ++m)
                #pragma unroll
                for (int n = 0; n < 4; ++n)
                    acc[m][n] = __builtin_amdgcn_mfma_f32_16x16x32_bf16(af[m], bfm[n], acc[m][n], 0, 0, 0);
        }
        __syncthreads();
    }

    const int colbase = col0 + wn*64;
    float bv[4];
    #pragma unroll
    for (int nt = 0; nt < 4; ++nt) bv[nt] = bias[colbase + nt*16 + l15];
    #pragma unroll
    for (int m = 0; m < 4; ++m)
        #pragma unroll
        for (int nt = 0; nt < 4; ++nt)
            #pragma unroll
            for (int r = 0; r < 4; ++r) acc[m][nt][r] += bv[nt];

    if (MODE == 1) {
        const float freq = exp2f(-(float)l15 * 0.83048202372184058696f);
        const int a0 = ((colbase >> 5) + 0) % 3;
        const int a1 = ((colbase >> 5) + 1) % 3;
        const int F  = (colbase >> 4) & 1;
        #pragma unroll
        for (int m = 0; m < 4; ++m) {
            #pragma unroll
            for (int r = 0; r < 4; ++r) {
                int row = row0 + wm*64 + m*16 + lg*4 + r;
                const float* c3 = coords + (size_t)row * 3;
                float sn0, cs0, sn1, cs1;
                __sincosf(c3[a0] * freq, &sn0, &cs0);
                __sincosf(c3[a1] * freq, &sn1, &cs1);
                {
                    float A_ = F ? acc[m][1][r] : acc[m][0][r];
                    float B_ = F ? acc[m][0][r] : acc[m][1][r];
                    float x1 = A_*cs0 - B_*sn0, x2 = A_*sn0 + B_*cs0;
                    if (F) { acc[m][1][r] = x1; acc[m][0][r] = x2; }
                    else   { acc[m][0][r] = x1; acc[m][1][r] = x2; }
                }
                {
                    float A_ = F ? acc[m][3][r] : acc[m][2][r];
                    float B_ = F ? acc[m][2][r] : acc[m][3][r];
                    float x1 = A_*cs1 - B_*sn1, x2 = A_*sn1 + B_*cs1;
                    if (F) { acc[m][3][r] = x1; acc[m][2][r] = x2; }
                    else   { acc[m][2][r] = x1; acc[m][3][r] = x2; }
                }
            }
        }
    }

    if (MODE == 0) {
        float* o32 = (float*)out;
        #pragma unroll
        for (int m = 0; m < 4; ++m)
            #pragma unroll
            for (int r = 0; r < 4; ++r) {
                int row = row0 + wm*64 + m*16 + lg*4 + r;
                #pragma unroll
                for (int nt = 0; nt < 4; ++nt)
                    o32[(size_t)row*DM + colbase + nt*16 + l15] = acc[m][nt][r];
            }
    } else if (MODE == 3) {
        // re-transpose through LDS (Sh is dead): Cs[col][row] XOR-swizzled
        #pragma unroll
        for (int m = 0; m < 4; ++m)
            #pragma unroll
            for (int nt = 0; nt < 4; ++nt)
                #pragma unroll
                for (int r = 0; r < 4; ++r) {
                    int c  = wn*64 + nt*16 + l15;
                    int ri = wm*64 + m*16 + lg*4 + r;
                    *(ushort*)((char*)Sh + c*256 + (((ri>>3) ^ (c&7))<<4) + (ri&7)*2)
                        = f2bf(acc[m][nt][r]);
                }
        __syncthreads();
        ushort* o16 = (ushort*)out;
        #pragma unroll
        for (int e = 0; e < 8; ++e) {
            int idx = tid + 256*e;
            int c = idx >> 4, r8 = idx & 15;
            uint4 val = *(const uint4*)((const char*)Sh + c*256 + ((r8 ^ (c&7))<<4));
            int j = col0 + c;
            int h = j / HD, t = j % HD;
            int row = row0 + r8*8;
            int b = row >> 12, l = row & (LK-1);
            *(uint4*)&o16[(((size_t)b*NH + h)*HD + t)*LK + l] = val;
        }
    } else {
        ushort* o16 = (ushort*)out;
        const int Lm1 = (1 << Lshift) - 1;
        int hh[4], tt[4];
        #pragma unroll
        for (int nt = 0; nt < 4; ++nt) {
            int j0 = colbase + nt*16;
            hh[nt] = j0 / HD;
            tt[nt] = j0 % HD + l15;
        }
        #pragma unroll
        for (int m = 0; m < 4; ++m)
            #pragma unroll
            for (int r = 0; r < 4; ++r) {
                int row = row0 + wm*64 + m*16 + lg*4 + r;
                int b = row >> Lshift, l = row & Lm1;
                #pragma unroll
                for (int nt = 0; nt < 4; ++nt)
                    o16[(((size_t)b*NH + hh[nt]) << Lshift | l) * HD + tt[nt]] =
                        f2bf(acc[m][nt][r]);
            }
    }
}

// MFMA flash attention, KV-split, swapped-QK^T softmax.
// Block = 4 waves x 64 q-rows; KVBLK=64. Reg-staged prefetch; XOR-swizzled K/V LDS.
// Writes unnormalized partial O (fp32) + per-row m,l.
__global__ __launch_bounds__(256, 4)
void attn_mfma(const ushort* __restrict__ q, const ushort* __restrict__ k,
               const ushort* __restrict__ vt, float* __restrict__ op,
               float* __restrict__ mlb)
{
    __shared__ ushort Ks[64*128];     // 16 KB, slot^=(row&7)
    __shared__ ushort Vs[96*64];      // 12 KB, slot^=(row&7)
    __shared__ ushort PsT[4][16][72]; // 9 KB: [wave][q][key]

    const int tid  = threadIdx.x;
    const int w    = tid >> 6;
    const int lane = tid & 63;
    const int l15  = lane & 15;
    const int lg   = lane >> 4;

    const int qt = blockIdx.x;
    const int bh = blockIdx.y;
    const int sc = blockIdx.z;

    const ushort* qg = q  + ((size_t)bh * LQ + qt*64 + w*16 + l15) * HD;
    const ushort* kg = k  + ((size_t)bh * LK + (size_t)sc * KC) * HD;
    const ushort* vg = vt + (size_t)bh * HD * LK + (size_t)sc * KC;

    short8v aq[3];
    #pragma unroll
    for (int dc = 0; dc < 3; ++dc)
        aq[dc] = *(const short8v*)(qg + dc*32 + lg*8);

    int kdst[3], ksrc[3], vdst[3], vsrc[3];
    #pragma unroll
    for (int j = 0; j < 3; ++j) {
        int c = tid + 256*j;
        int kr = c / 12, ks = c % 12;
        kdst[j] = kr*256 + ((ks ^ (kr & 7)) << 4);
        ksrc[j] = kr*HD + ks*8;
        int vr = c >> 3, vs = c & 7;
        vdst[j] = vr*128 + ((vs ^ (vr & 7)) << 4);
        vsrc[j] = vr*LK + vs*8;
    }
    int tK[3], tV[2];
    #pragma unroll
    for (int dc = 0; dc < 3; ++dc) tK[dc] = ((dc*4 + lg) ^ (l15 & 7)) << 4;
    #pragma unroll
    for (int h2 = 0; h2 < 2; ++h2)  tV[h2] = ((h2*4 + lg) ^ (l15 & 7)) << 4;

    float4v o[6];
    #pragma unroll
    for (int dt = 0; dt < 6; ++dt) o[dt] = (float4v)0.f;
    float m_p = -1e30f, l_p = 0.f;       // scalar per lane: q = l15

    const float scale = 0.10206207261596575f;  // 1/sqrt(96)

    short8v kreg[3], vreg[3];
    #pragma unroll
    for (int j = 0; j < 3; ++j) {
        kreg[j] = *(const short8v*)(kg + ksrc[j]);
        vreg[j] = *(const short8v*)(vg + vsrc[j]);
    }
    #pragma unroll
    for (int j = 0; j < 3; ++j) {
        *(short8v*)((char*)Ks + kdst[j]) = kreg[j];
        *(short8v*)((char*)Vs + vdst[j]) = vreg[j];
    }
    __syncthreads();

    for (int t = 0; t < NT; ++t) {
        if (t + 1 < NT) {
            const ushort* kn = kg + (size_t)(t+1)*64*HD;
            const ushort* vn = vg + (t+1)*64;
            #pragma unroll
            for (int j = 0; j < 3; ++j) {
                kreg[j] = *(const short8v*)(kn + ksrc[j]);
                vreg[j] = *(const short8v*)(vn + vsrc[j]);
            }
        }

        // ---- S^T = K Q^T : lane holds q=l15, keys nt*16 + lg*4 + r ----
        float4v s[4];
        __builtin_amdgcn_s_setprio(1);
        #pragma unroll
        for (int nt = 0; nt < 4; ++nt) {
            s[nt] = (float4v)0.f;
            #pragma unroll
            for (int dc = 0; dc < 3; ++dc) {
                short8v bk = *(const short8v*)((const char*)Ks + nt*4096 + l15*256 + tK[dc]);
                s[nt] = __builtin_amdgcn_mfma_f32_16x16x32_bf16(bk, aq[dc], s[nt], 0, 0, 0);
            }
        }
        __builtin_amdgcn_s_setprio(0);

        // ---- online softmax: in-lane reduce + 2 shuffles ----
        float mt = -1e30f;
        #pragma unroll
        for (int nt = 0; nt < 4; ++nt)
            #pragma unroll
            for (int r = 0; r < 4; ++r) {
                s[nt][r] *= scale;
                mt = fmaxf(mt, s[nt][r]);
            }
        mt = fmaxf(mt, __shfl_xor(mt, 16, 64));
        mt = fmaxf(mt, __shfl_xor(mt, 32, 64));

        if (__any(mt > m_p + 8.f)) {        // defer-max: rescale only when needed
            float mn = fmaxf(m_p, mt);
            float alpha = __expf(m_p - mn);
            m_p = mn;
            l_p *= alpha;
            float al[4];
            #pragma unroll
            for (int r = 0; r < 4; ++r) al[r] = __shfl(alpha, lg*4 + r, 64);
            #pragma unroll
            for (int dt = 0; dt < 6; ++dt)
                #pragma unroll
                for (int r = 0; r < 4; ++r) o[dt][r] *= al[r];
        }

        float psum = 0.f;
        #pragma unroll
        for (int nt = 0; nt < 4; ++nt)
            #pragma unroll
            for (int r = 0; r < 4; ++r) {
                float p = __expf(s[nt][r] - m_p);
                s[nt][r] = p;
                psum += p;
            }
        psum += __shfl_xor(psum, 16, 64);
        psum += __shfl_xor(psum, 32, 64);
        l_p += psum;

        // ---- pack P^T rows: 8 cvt_pk + 4 ds_write_b64 ----
        #pragma unroll
        for (int nt = 0; nt < 4; ++nt) {
            uint2 pk;
            pk.x = cvtpk(s[nt][0], s[nt][1]);
            pk.y = cvtpk(s[nt][2], s[nt][3]);
            *(uint2*)&PsT[w][l15][nt*16 + lg*4] = pk;
        }

        // ---- O += P V  (PsT same-wave roundtrip) ----
        short8v ap0 = *(const short8v*)&PsT[w][l15][lg*8];
        short8v ap1 = *(const short8v*)&PsT[w][l15][32 + lg*8];
        __builtin_amdgcn_s_setprio(1);
        #pragma unroll
        for (int dt = 0; dt < 6; ++dt) {
            short8v bv0 = *(const short8v*)((const char*)Vs + dt*2048 + l15*128 + tV[0]);
            short8v bv1 = *(const short8v*)((const char*)Vs + dt*2048 + l15*128 + tV[1]);
            o[dt] = __builtin_amdgcn_mfma_f32_16x16x32_bf16(ap0, bv0, o[dt], 0, 0, 0);
            o[dt] = __builtin_amdgcn_mfma_f32_16x16x32_bf16(ap1, bv1, o[dt], 0, 0, 0);
        }
        __builtin_amdgcn_s_setprio(0);
        __syncthreads();

        if (t + 1 < NT) {
            #pragma unroll
            for (int j = 0; j < 3; ++j) {
                *(short8v*)((char*)Ks + kdst[j]) = kreg[j];
                *(short8v*)((char*)Vs + vdst[j]) = vreg[j];
            }
        }
        __syncthreads();
    }

    // ---- epilogue: unnormalized partials (q = lg*4+r, d = dt*16+l15) ----
    float* ob = op + (((size_t)sc * BH + bh) * LQ + qt*64 + w*16) * HD;
    #pragma unroll
    for (int r = 0; r < 4; ++r) {
        int row = lg*4 + r;
        #pragma unroll
        for (int dt = 0; dt < 6; ++dt)
            ob[(size_t)row * HD + dt*16 + l15] = o[dt][r];
    }
    if (lane < 16) {
        size_t mlrow = ((size_t)sc * BH + bh) * LQ + qt*64 + w*16 + lane;
        mlb[mlrow*2 + 0] = m_p;
        mlb[mlrow*2 + 1] = l_p;
    }
}

// merge KVS=2 partials -> ctx bf16 (B, LQ, 768)
__global__ __launch_bounds__(256)
void combine(const float* __restrict__ op, const float* __restrict__ mlb,
             ushort* __restrict__ ctx)
{
    const int NROW = BH * LQ;
    int idx = blockIdx.x * 256 + threadIdx.x;
    int row = idx / 12, seg = idx % 12;
    float m0 = mlb[(size_t)row*2],          l0 = mlb[(size_t)row*2 + 1];
    float m1 = mlb[(size_t)(NROW + row)*2], l1 = mlb[(size_t)(NROW + row)*2 + 1];
    float ms = fmaxf(m0, m1);
    float w0 = __expf(m0 - ms), w1 = __expf(m1 - ms);
    float inv = 1.f / (l0*w0 + l1*w1);
    const float4* p0 = (const float4*)(op + (size_t)row*HD + seg*8);
    const float4* p1 = (const float4*)(op + (size_t)(NROW + row)*HD + seg*8);
    float4 a0 = p0[0], a1 = p0[1];
    float4 b0 = p1[0], b1 = p1[1];
    float r0 = (a0.x*w0 + b0.x*w1)*inv, r1 = (a0.y*w0 + b0.y*w1)*inv;
    float r2 = (a0.z*w0 + b0.z*w1)*inv, r3 = (a0.w*w0 + b0.w*w1)*inv;
    float r4 = (a1.x*w0 + b1.x*w1)*inv, r5 = (a1.y*w0 + b1.y*w1)*inv;
    float r6 = (a1.z*w0 + b1.z*w1)*inv, r7 = (a1.w*w0 + b1.w*w1)*inv;
    int bh = row / LQ, l = row % LQ;
    int b = bh >> 3, h = bh & 7;
    ushort* o = ctx + ((size_t)b * LQ + l) * DM + h * HD + seg*8;
    uint4 pk;
    pk.x = (uint)f2bf(r0) | ((uint)f2bf(r1) << 16);
    pk.y = (uint)f2bf(r2) | ((uint)f2bf(r3) << 16);
    pk.z = (uint)f2bf(r4) | ((uint)f2bf(r5) << 16);
    pk.w = (uint)f2bf(r6) | ((uint)f2bf(r7) << 16);
    *(uint4*)o = pk;
}

extern "C" void kernel_launch(void* const* d_in, const int* in_sizes, int n_in,
                              void* d_out, int out_size, void* d_ws, size_t ws_size,
                              hipStream_t stream)
{
    const float* query = (const float*)d_in[0];
    const float* key   = (const float*)d_in[1];
    const float* value = (const float*)d_in[2];
    const float* cq    = (const float*)d_in[3];
    const float* ck    = (const float*)d_in[4];
    const float* Wq    = (const float*)d_in[5];
    const float* bqv   = (const float*)d_in[6];
    const float* Wk    = (const float*)d_in[7];
    const float* bkv   = (const float*)d_in[8];
    const float* Wv    = (const float*)d_in[9];
    const float* bvv   = (const float*)d_in[10];
    const float* Wo    = (const float*)d_in[11];
    const float* bov   = (const float*)d_in[12];
    float* out = (float*)d_out;

    const size_t NQ = (size_t)BQ * LQ * DM;
    const size_t NK = (size_t)BQ * LK * DM;
    const size_t NW = (size_t)DM * DM;

    ushort* qx  = (ushort*)d_ws;
    ushort* kx  = qx  + NQ;
    ushort* vx  = kx  + NK;
    ushort* wq  = vx  + NK;
    ushort* wk  = wq  + NW;
    ushort* wv  = wk  + NW;
    ushort* wo  = wv  + NW;
    ushort* qws = wo  + NW;
    ushort* kws = qws + NQ;
    ushort* vws = kws + NK;
    ushort* vtb = kx;                 // overlays kx (dead after gemm_k)
    ushort* ctx = qx;                 // overlays qx (dead after gemm_q)
    float*  op  = (float*)vws;        // overlays vws (unused for data now)
    float*  mlb = (float*)vx;         // overlays vx (dead after gemm_v)

    cvt_bf16<<<(int)(NQ/4/256), 256, 0, stream>>>(query, qx);
    cvt_bf16<<<(int)(NK/4/256), 256, 0, stream>>>(key,   kx);
    cvt_bf16<<<(int)(NK/4/256), 256, 0, stream>>>(value, vx);
    cvt_bf16<<<(int)(NW/4/256), 256, 0, stream>>>(Wq, wq);
    cvt_bf16<<<(int)(NW/4/256), 256, 0, stream>>>(Wk, wk);
    cvt_bf16<<<(int)(NW/4/256), 256, 0, stream>>>(Wv, wv);
    cvt_bf16<<<(int)(NW/4/256), 256, 0, stream>>>(Wo, wo);

    gemm_mfma<1><<<dim3(DM/128, BQ*LQ/128), 256, 0, stream>>>(qx, wq, bqv, cq, qws, 10);
    gemm_mfma<1><<<dim3(DM/128, BQ*LK/128), 256, 0, stream>>>(kx, wk, bkv, ck, kws, 12);
    gemm_mfma<3><<<dim3(DM/128, BQ*LK/128), 256, 0, stream>>>(vx, wv, bvv, nullptr, vtb, 12);
    attn_mfma<<<dim3(LQ/64, BH, KVS), 256, 0, stream>>>(qws, kws, vtb, op, mlb);
    combine<<<BH*LQ*12/256, 256, 0, stream>>>(op, mlb, ctx);
    gemm_mfma<0><<<dim3(DM/128, BQ*LQ/128), 256, 0, stream>>>(ctx, wo, bov, nullptr, out, 0);
}

// Round 6
// 239.784 us; speedup vs baseline: 9.0485x; 1.0936x over previous
//
#include <hip/hip_runtime.h>
#include <math.h>

#define DM 768
#define NH 8
#define HD 96
#define BQ 4
#define LQ 1024
#define LK 4096
#define BH (BQ*NH)
#define KVS 2              // kv-split factor
#define KC (LK/KVS)        // keys per chunk
#define NT (KC/64)         // 64-key tiles per block
#define QB 128             // q-rows per block (32 per wave)

typedef unsigned short ushort;
typedef unsigned int uint;
typedef __attribute__((ext_vector_type(8))) short short8v;
typedef __attribute__((ext_vector_type(4))) float float4v;

// 1/sqrt(96) * log2(e)  (folded into Q projection)
#define QSCALE 0.14724444641f

static __device__ __forceinline__ ushort f2bf(float x) {
    union { float f; uint u; } c; c.f = x;
    uint u = c.u;
    u += ((u >> 16) & 1u) + 0x7fffu;   // RNE
    return (ushort)(u >> 16);
}

static __device__ __forceinline__ uint cvtpk(float lo, float hi) {
    uint d;
    asm("v_cvt_pk_bf16_f32 %0, %1, %2" : "=v"(d) : "v"(lo), "v"(hi));
    return d;
}

static __device__ __forceinline__ float exp2hw(float x) {
#if __has_builtin(__builtin_amdgcn_exp2f)
    return __builtin_amdgcn_exp2f(x);
#else
    return __expf(x * 0.6931471805599453f);
#endif
}

static __device__ __forceinline__ void gload_lds16(const ushort* g, ushort* l) {
    __builtin_amdgcn_global_load_lds(
        (const __attribute__((address_space(1))) uint*)g,
        (__attribute__((address_space(3))) uint*)l, 16, 0, 0);
}

// fp32 -> bf16, 4 elems/thread
__global__ __launch_bounds__(256)
void cvt_bf16(const float* __restrict__ s, ushort* __restrict__ d)
{
    int i = blockIdx.x * 256 + threadIdx.x;
    float4 v = ((const float4*)s)[i];
    uint2 o;
    o.x = (uint)f2bf(v.x) | ((uint)f2bf(v.y) << 16);
    o.y = (uint)f2bf(v.z) | ((uint)f2bf(v.w) << 16);
    ((uint2*)d)[i] = o;
}

// bf16 MFMA GEMM: C = X @ W^T + b, 128x128xBK64.
// MODE 0: fp32 row-major. MODE 1: RoPE (+oscale) + bf16 (B,H,L,96). MODE 2: bf16 (B,H,L,96).
// MODE 3: bf16 V^T (B,H,96,LK) via LDS re-transpose of the C tile.
template<int MODE>
__global__ __launch_bounds__(256)
void gemm_mfma(const ushort* __restrict__ X, const ushort* __restrict__ Wb,
               const float* __restrict__ bias, const float* __restrict__ coords,
               void* __restrict__ out, int Lshift, float oscale)
{
    __shared__ ushort Sh[16384];     // As = Sh[0:8192], Bs = Sh[8192:16384]
    ushort* As = Sh;
    ushort* Bs = Sh + 8192;

    const int tid  = threadIdx.x;
    const int w    = tid >> 6;
    const int lane = tid & 63;
    const int l15  = lane & 15;
    const int lg   = lane >> 4;
    const int wm   = w >> 1, wn = w & 1;
    const int col0 = blockIdx.x * 128;
    const int row0 = blockIdx.y * 128;

    float4v acc[4][4];
    #pragma unroll
    for (int m = 0; m < 4; ++m)
        #pragma unroll
        for (int n = 0; n < 4; ++n) acc[m][n] = (float4v)0.f;

    int Pp[4], rrS[4], cbS[4];
    #pragma unroll
    for (int c = 0; c < 4; ++c) {
        int P = ((w*4 + c) << 10) + lane*16;
        int lgc = P ^ (((P >> 9) & 3) << 5);
        Pp[c]  = P;
        rrS[c] = lgc >> 7;
        cbS[c] = (lgc & 127) >> 1;
    }
    const ushort* xb = X  + (size_t)row0 * DM;
    const ushort* wb = Wb + (size_t)col0 * DM;

    int offA[2][4], offB[2][4];
    #pragma unroll
    for (int kk = 0; kk < 2; ++kk) {
        #pragma unroll
        for (int m = 0; m < 4; ++m) {
            int byte = (wm*64 + m*16 + l15)*128 + kk*64 + lg*16;
            offA[kk][m] = byte ^ (((byte >> 9) & 3) << 5);
            byte = (wn*64 + m*16 + l15)*128 + kk*64 + lg*16;
            offB[kk][m] = byte ^ (((byte >> 9) & 3) << 5);
        }
    }

    for (int kt = 0; kt < DM; kt += 64) {
        #pragma unroll
        for (int c = 0; c < 4; ++c) {
            gload_lds16(xb + (size_t)rrS[c]*DM + kt + cbS[c], (ushort*)((char*)As + Pp[c]));
            gload_lds16(wb + (size_t)rrS[c]*DM + kt + cbS[c], (ushort*)((char*)Bs + Pp[c]));
        }
        __syncthreads();
        #pragma unroll
        for (int kk = 0; kk < 2; ++kk) {
            short8v af[4], bfm[4];
            #pragma unroll
            for (int m = 0; m < 4; ++m)
                af[m] = *(const short8v*)((const char*)As + offA[kk][m]);
            #pragma unroll
            for (int n = 0; n < 4; ++n)
                bfm[n] = *(const short8v*)((const char*)Bs + offB[kk][n]);
            #pragma unroll
            for (int m = 0; m < 4; ++m)
                #pragma unroll
                for (int n = 0; n < 4; ++n)
                    acc[m][n] = __builtin_amdgcn_mfma_f32_16x16x32_bf16(af[m], bfm[n], acc[m][n], 0, 0, 0);
        }
        __syncthreads();
    }

    const int colbase = col0 + wn*64;
    float bv[4];
    #pragma unroll
    for (int nt = 0; nt < 4; ++nt) bv[nt] = bias[colbase + nt*16 + l15];
    #pragma unroll
    for (int m = 0; m < 4; ++m)
        #pragma unroll
        for (int nt = 0; nt < 4; ++nt)
            #pragma unroll
            for (int r = 0; r < 4; ++r) acc[m][nt][r] += bv[nt];

    if (MODE == 1) {
        const float freq = exp2f(-(float)l15 * 0.83048202372184058696f);
        const int a0 = ((colbase >> 5) + 0) % 3;
        const int a1 = ((colbase >> 5) + 1) % 3;
        const int F  = (colbase >> 4) & 1;
        #pragma unroll
        for (int m = 0; m < 4; ++m) {
            #pragma unroll
            for (int r = 0; r < 4; ++r) {
                int row = row0 + wm*64 + m*16 + lg*4 + r;
                const float* c3 = coords + (size_t)row * 3;
                float sn0, cs0, sn1, cs1;
                __sincosf(c3[a0] * freq, &sn0, &cs0);
                __sincosf(c3[a1] * freq, &sn1, &cs1);
                {
                    float A_ = F ? acc[m][1][r] : acc[m][0][r];
                    float B_ = F ? acc[m][0][r] : acc[m][1][r];
                    float x1 = (A_*cs0 - B_*sn0) * oscale, x2 = (A_*sn0 + B_*cs0) * oscale;
                    if (F) { acc[m][1][r] = x1; acc[m][0][r] = x2; }
                    else   { acc[m][0][r] = x1; acc[m][1][r] = x2; }
                }
                {
                    float A_ = F ? acc[m][3][r] : acc[m][2][r];
                    float B_ = F ? acc[m][2][r] : acc[m][3][r];
                    float x1 = (A_*cs1 - B_*sn1) * oscale, x2 = (A_*sn1 + B_*cs1) * oscale;
                    if (F) { acc[m][3][r] = x1; acc[m][2][r] = x2; }
                    else   { acc[m][2][r] = x1; acc[m][3][r] = x2; }
                }
            }
        }
    }

    if (MODE == 0) {
        float* o32 = (float*)out;
        #pragma unroll
        for (int m = 0; m < 4; ++m)
            #pragma unroll
            for (int r = 0; r < 4; ++r) {
                int row = row0 + wm*64 + m*16 + lg*4 + r;
                #pragma unroll
                for (int nt = 0; nt < 4; ++nt)
                    o32[(size_t)row*DM + colbase + nt*16 + l15] = acc[m][nt][r];
            }
    } else if (MODE == 3) {
        // re-transpose through LDS (Sh is dead): Cs[col][row] XOR-swizzled
        #pragma unroll
        for (int m = 0; m < 4; ++m)
            #pragma unroll
            for (int nt = 0; nt < 4; ++nt)
                #pragma unroll
                for (int r = 0; r < 4; ++r) {
                    int c  = wn*64 + nt*16 + l15;
                    int ri = wm*64 + m*16 + lg*4 + r;
                    *(ushort*)((char*)Sh + c*256 + (((ri>>3) ^ (c&7))<<4) + (ri&7)*2)
                        = f2bf(acc[m][nt][r]);
                }
        __syncthreads();
        ushort* o16 = (ushort*)out;
        #pragma unroll
        for (int e = 0; e < 8; ++e) {
            int idx = tid + 256*e;
            int c = idx >> 4, r8 = idx & 15;
            uint4 val = *(const uint4*)((const char*)Sh + c*256 + ((r8 ^ (c&7))<<4));
            int j = col0 + c;
            int h = j / HD, t = j % HD;
            int row = row0 + r8*8;
            int b = row >> 12, l = row & (LK-1);
            *(uint4*)&o16[(((size_t)b*NH + h)*HD + t)*LK + l] = val;
        }
    } else {
        ushort* o16 = (ushort*)out;
        const int Lm1 = (1 << Lshift) - 1;
        int hh[4], tt[4];
        #pragma unroll
        for (int nt = 0; nt < 4; ++nt) {
            int j0 = colbase + nt*16;
            hh[nt] = j0 / HD;
            tt[nt] = j0 % HD + l15;
        }
        #pragma unroll
        for (int m = 0; m < 4; ++m)
            #pragma unroll
            for (int r = 0; r < 4; ++r) {
                int row = row0 + wm*64 + m*16 + lg*4 + r;
                int b = row >> Lshift, l = row & Lm1;
                #pragma unroll
                for (int nt = 0; nt < 4; ++nt)
                    o16[(((size_t)b*NH + hh[nt]) << Lshift | l) * HD + tt[nt]] =
                        f2bf(acc[m][nt][r]);
            }
    }
}

// MFMA flash attention, KV-split, swapped-QK^T, exp2-domain softmax.
// Block = 4 waves x 128 q-rows (wave owns 32 = 2 fragments); KVBLK=64.
// XCD-pair swizzle: all 8 qt-blocks of one (bh,sc) land on one XCD.
// Scores arrive pre-scaled by 1/sqrt(96)*log2e (folded into Q).
__global__ __launch_bounds__(256, 2)
void attn_mfma(const ushort* __restrict__ q, const ushort* __restrict__ k,
               const ushort* __restrict__ vt, float* __restrict__ op,
               float* __restrict__ mlb)
{
    __shared__ ushort Ks[64*128];     // 16 KB, slot^=(row&7)
    __shared__ ushort Vs[96*64];      // 12 KB, slot^=(row&7)
    __shared__ ushort PsT[4][32][72]; // 18 KB: [wave][q][key]

    const int tid  = threadIdx.x;
    const int w    = tid >> 6;
    const int lane = tid & 63;
    const int l15  = lane & 15;
    const int lg   = lane >> 4;

    // decode: same (bh,sc) -> same XCD (L&7); qt sequential within XCD
    const int L   = blockIdx.x;
    const int seq = L >> 3;
    const int pr  = (L & 7) * 8 + (seq >> 3);   // 0..63
    const int qt  = seq & 7;
    const int bh  = pr & 31;
    const int sc  = pr >> 5;

    const ushort* qg = q  + ((size_t)bh * LQ + qt*QB + w*32 + l15) * HD;
    const ushort* kg = k  + ((size_t)bh * LK + (size_t)sc * KC) * HD;
    const ushort* vg = vt + (size_t)bh * HD * LK + (size_t)sc * KC;

    short8v aq0[3], aq1[3];
    #pragma unroll
    for (int dc = 0; dc < 3; ++dc) {
        aq0[dc] = *(const short8v*)(qg + dc*32 + lg*8);
        aq1[dc] = *(const short8v*)(qg + 16*HD + dc*32 + lg*8);
    }

    int kdst[3], ksrc[3], vdst[3], vsrc[3];
    #pragma unroll
    for (int j = 0; j < 3; ++j) {
        int c = tid + 256*j;
        int kr = c / 12, ks = c % 12;
        kdst[j] = kr*256 + ((ks ^ (kr & 7)) << 4);
        ksrc[j] = kr*HD + ks*8;
        int vr = c >> 3, vs = c & 7;
        vdst[j] = vr*128 + ((vs ^ (vr & 7)) << 4);
        vsrc[j] = vr*LK + vs*8;
    }
    int tK[3], tV[2];
    #pragma unroll
    for (int dc = 0; dc < 3; ++dc) tK[dc] = ((dc*4 + lg) ^ (l15 & 7)) << 4;
    #pragma unroll
    for (int h2 = 0; h2 < 2; ++h2)  tV[h2] = ((h2*4 + lg) ^ (l15 & 7)) << 4;

    float4v o0[6], o1[6];
    #pragma unroll
    for (int dt = 0; dt < 6; ++dt) { o0[dt] = (float4v)0.f; o1[dt] = (float4v)0.f; }
    float m_0 = -1e30f, l_0 = 0.f;   // q = l15       (log2 domain)
    float m_1 = -1e30f, l_1 = 0.f;   // q = 16 + l15

    short8v kreg[3], vreg[3];
    #pragma unroll
    for (int j = 0; j < 3; ++j) {
        kreg[j] = *(const short8v*)(kg + ksrc[j]);
        vreg[j] = *(const short8v*)(vg + vsrc[j]);
    }
    #pragma unroll
    for (int j = 0; j < 3; ++j) {
        *(short8v*)((char*)Ks + kdst[j]) = kreg[j];
        *(short8v*)((char*)Vs + vdst[j]) = vreg[j];
    }
    __syncthreads();

    for (int t = 0; t < NT; ++t) {
        if (t + 1 < NT) {
            const ushort* kn = kg + (size_t)(t+1)*64*HD;
            const ushort* vn = vg + (t+1)*64;
            #pragma unroll
            for (int j = 0; j < 3; ++j) {
                kreg[j] = *(const short8v*)(kn + ksrc[j]);
                vreg[j] = *(const short8v*)(vn + vsrc[j]);
            }
        }

        // ---- S^T = K Q^T : lane holds q=l15 (frag0) / 16+l15 (frag1) ----
        float4v s0[4], s1[4];
        __builtin_amdgcn_s_setprio(1);
        #pragma unroll
        for (int nt = 0; nt < 4; ++nt) {
            s0[nt] = (float4v)0.f;
            s1[nt] = (float4v)0.f;
            #pragma unroll
            for (int dc = 0; dc < 3; ++dc) {
                short8v bk = *(const short8v*)((const char*)Ks + nt*4096 + l15*256 + tK[dc]);
                s0[nt] = __builtin_amdgcn_mfma_f32_16x16x32_bf16(bk, aq0[dc], s0[nt], 0, 0, 0);
                s1[nt] = __builtin_amdgcn_mfma_f32_16x16x32_bf16(bk, aq1[dc], s1[nt], 0, 0, 0);
            }
        }
        __builtin_amdgcn_s_setprio(0);

        // ---- online softmax (log2 domain, no scale muls) ----
        float mt0 = -1e30f, mt1 = -1e30f;
        #pragma unroll
        for (int nt = 0; nt < 4; ++nt)
            #pragma unroll
            for (int r = 0; r < 4; ++r) {
                mt0 = fmaxf(mt0, s0[nt][r]);
                mt1 = fmaxf(mt1, s1[nt][r]);
            }
        mt0 = fmaxf(mt0, __shfl_xor(mt0, 16, 64));
        mt0 = fmaxf(mt0, __shfl_xor(mt0, 32, 64));
        mt1 = fmaxf(mt1, __shfl_xor(mt1, 16, 64));
        mt1 = fmaxf(mt1, __shfl_xor(mt1, 32, 64));

        if (__any((mt0 > m_0 + 11.5f) || (mt1 > m_1 + 11.5f))) {
            float mn0 = fmaxf(m_0, mt0), mn1 = fmaxf(m_1, mt1);
            float a0 = exp2hw(m_0 - mn0), a1 = exp2hw(m_1 - mn1);
            m_0 = mn0; m_1 = mn1;
            l_0 *= a0;  l_1 *= a1;
            float al0[4], al1[4];
            #pragma unroll
            for (int r = 0; r < 4; ++r) {
                al0[r] = __shfl(a0, lg*4 + r, 64);
                al1[r] = __shfl(a1, lg*4 + r, 64);
            }
            #pragma unroll
            for (int dt = 0; dt < 6; ++dt)
                #pragma unroll
                for (int r = 0; r < 4; ++r) {
                    o0[dt][r] *= al0[r];
                    o1[dt][r] *= al1[r];
                }
        }

        float ps0 = 0.f, ps1 = 0.f;
        #pragma unroll
        for (int nt = 0; nt < 4; ++nt)
            #pragma unroll
            for (int r = 0; r < 4; ++r) {
                float p0 = exp2hw(s0[nt][r] - m_0);
                float p1 = exp2hw(s1[nt][r] - m_1);
                s0[nt][r] = p0; ps0 += p0;
                s1[nt][r] = p1; ps1 += p1;
            }
        ps0 += __shfl_xor(ps0, 16, 64);
        ps0 += __shfl_xor(ps0, 32, 64);
        ps1 += __shfl_xor(ps1, 16, 64);
        ps1 += __shfl_xor(ps1, 32, 64);
        l_0 += ps0;
        l_1 += ps1;

        // ---- pack P^T rows ----
        #pragma unroll
        for (int nt = 0; nt < 4; ++nt) {
            uint2 pk0, pk1;
            pk0.x = cvtpk(s0[nt][0], s0[nt][1]);
            pk0.y = cvtpk(s0[nt][2], s0[nt][3]);
            pk1.x = cvtpk(s1[nt][0], s1[nt][1]);
            pk1.y = cvtpk(s1[nt][2], s1[nt][3]);
            *(uint2*)&PsT[w][l15][nt*16 + lg*4]      = pk0;
            *(uint2*)&PsT[w][16 + l15][nt*16 + lg*4] = pk1;
        }

        // ---- O += P V  (Vs fragments shared between both q-frags) ----
        short8v a00 = *(const short8v*)&PsT[w][l15][lg*8];
        short8v a01 = *(const short8v*)&PsT[w][l15][32 + lg*8];
        short8v a10 = *(const short8v*)&PsT[w][16 + l15][lg*8];
        short8v a11 = *(const short8v*)&PsT[w][16 + l15][32 + lg*8];
        __builtin_amdgcn_s_setprio(1);
        #pragma unroll
        for (int dt = 0; dt < 6; ++dt) {
            short8v bv0 = *(const short8v*)((const char*)Vs + dt*2048 + l15*128 + tV[0]);
            short8v bv1 = *(const short8v*)((const char*)Vs + dt*2048 + l15*128 + tV[1]);
            o0[dt] = __builtin_amdgcn_mfma_f32_16x16x32_bf16(a00, bv0, o0[dt], 0, 0, 0);
            o0[dt] = __builtin_amdgcn_mfma_f32_16x16x32_bf16(a01, bv1, o0[dt], 0, 0, 0);
            o1[dt] = __builtin_amdgcn_mfma_f32_16x16x32_bf16(a10, bv0, o1[dt], 0, 0, 0);
            o1[dt] = __builtin_amdgcn_mfma_f32_16x16x32_bf16(a11, bv1, o1[dt], 0, 0, 0);
        }
        __builtin_amdgcn_s_setprio(0);
        __syncthreads();

        if (t + 1 < NT) {
            #pragma unroll
            for (int j = 0; j < 3; ++j) {
                *(short8v*)((char*)Ks + kdst[j]) = kreg[j];
                *(short8v*)((char*)Vs + vdst[j]) = vreg[j];
            }
        }
        __syncthreads();
    }

    // ---- epilogue: unnormalized partials ----
    float* ob = op + (((size_t)sc * BH + bh) * LQ + qt*QB + w*32) * HD;
    #pragma unroll
    for (int r = 0; r < 4; ++r) {
        #pragma unroll
        for (int dt = 0; dt < 6; ++dt) {
            ob[(size_t)(lg*4 + r) * HD + dt*16 + l15]      = o0[dt][r];
            ob[(size_t)(16 + lg*4 + r) * HD + dt*16 + l15] = o1[dt][r];
        }
    }
    if (lane < 16) {
        size_t mlrow = ((size_t)sc * BH + bh) * LQ + qt*QB + w*32 + lane;
        mlb[mlrow*2 + 0] = m_0;
        mlb[mlrow*2 + 1] = l_0;
        mlb[(mlrow + 16)*2 + 0] = m_1;
        mlb[(mlrow + 16)*2 + 1] = l_1;
    }
}

// merge KVS=2 partials -> ctx bf16 (B, LQ, 768); m,l in log2 domain
__global__ __launch_bounds__(256)
void combine(const float* __restrict__ op, const float* __restrict__ mlb,
             ushort* __restrict__ ctx)
{
    const int NROW = BH * LQ;
    int idx = blockIdx.x * 256 + threadIdx.x;
    int row = idx / 12, seg = idx % 12;
    float m0 = mlb[(size_t)row*2],          l0 = mlb[(size_t)row*2 + 1];
    float m1 = mlb[(size_t)(NROW + row)*2], l1 = mlb[(size_t)(NROW + row)*2 + 1];
    float ms = fmaxf(m0, m1);
    float w0 = exp2hw(m0 - ms), w1 = exp2hw(m1 - ms);
    float inv = 1.f / (l0*w0 + l1*w1);
    const float4* p0 = (const float4*)(op + (size_t)row*HD + seg*8);
    const float4* p1 = (const float4*)(op + (size_t)(NROW + row)*HD + seg*8);
    float4 a0 = p0[0], a1 = p0[1];
    float4 b0 = p1[0], b1 = p1[1];
    float r0 = (a0.x*w0 + b0.x*w1)*inv, r1 = (a0.y*w0 + b0.y*w1)*inv;
    float r2 = (a0.z*w0 + b0.z*w1)*inv, r3 = (a0.w*w0 + b0.w*w1)*inv;
    float r4 = (a1.x*w0 + b1.x*w1)*inv, r5 = (a1.y*w0 + b1.y*w1)*inv;
    float r6 = (a1.z*w0 + b1.z*w1)*inv, r7 = (a1.w*w0 + b1.w*w1)*inv;
    int bh = row / LQ, l = row % LQ;
    int b = bh >> 3, h = bh & 7;
    ushort* o = ctx + ((size_t)b * LQ + l) * DM + h * HD + seg*8;
    uint4 pk;
    pk.x = (uint)f2bf(r0) | ((uint)f2bf(r1) << 16);
    pk.y = (uint)f2bf(r2) | ((uint)f2bf(r3) << 16);
    pk.z = (uint)f2bf(r4) | ((uint)f2bf(r5) << 16);
    pk.w = (uint)f2bf(r6) | ((uint)f2bf(r7) << 16);
    *(uint4*)o = pk;
}

extern "C" void kernel_launch(void* const* d_in, const int* in_sizes, int n_in,
                              void* d_out, int out_size, void* d_ws, size_t ws_size,
                              hipStream_t stream)
{
    const float* query = (const float*)d_in[0];
    const float* key   = (const float*)d_in[1];
    const float* value = (const float*)d_in[2];
    const float* cq    = (const float*)d_in[3];
    const float* ck    = (const float*)d_in[4];
    const float* Wq    = (const float*)d_in[5];
    const float* bqv   = (const float*)d_in[6];
    const float* Wk    = (const float*)d_in[7];
    const float* bkv   = (const float*)d_in[8];
    const float* Wv    = (const float*)d_in[9];
    const float* bvv   = (const float*)d_in[10];
    const float* Wo    = (const float*)d_in[11];
    const float* bov   = (const float*)d_in[12];
    float* out = (float*)d_out;

    const size_t NQ = (size_t)BQ * LQ * DM;
    const size_t NK = (size_t)BQ * LK * DM;
    const size_t NW = (size_t)DM * DM;

    ushort* qx  = (ushort*)d_ws;
    ushort* kx  = qx  + NQ;
    ushort* vx  = kx  + NK;
    ushort* wq  = vx  + NK;
    ushort* wk  = wq  + NW;
    ushort* wv  = wk  + NW;
    ushort* wo  = wv  + NW;
    ushort* qws = wo  + NW;
    ushort* kws = qws + NQ;
    ushort* vws = kws + NK;
    ushort* vtb = kx;                 // overlays kx (dead after gemm_k)
    ushort* ctx = qx;                 // overlays qx (dead after gemm_q)
    float*  op  = (float*)vws;        // partial O: KVS * BH*LQ*HD fp32
    float*  mlb = (float*)vx;         // overlays vx (dead after gemm_v)

    cvt_bf16<<<(int)(NQ/4/256), 256, 0, stream>>>(query, qx);
    cvt_bf16<<<(int)(NK/4/256), 256, 0, stream>>>(key,   kx);
    cvt_bf16<<<(int)(NK/4/256), 256, 0, stream>>>(value, vx);
    cvt_bf16<<<(int)(NW/4/256), 256, 0, stream>>>(Wq, wq);
    cvt_bf16<<<(int)(NW/4/256), 256, 0, stream>>>(Wk, wk);
    cvt_bf16<<<(int)(NW/4/256), 256, 0, stream>>>(Wv, wv);
    cvt_bf16<<<(int)(NW/4/256), 256, 0, stream>>>(Wo, wo);

    gemm_mfma<1><<<dim3(DM/128, BQ*LQ/128), 256, 0, stream>>>(qx, wq, bqv, cq, qws, 10, QSCALE);
    gemm_mfma<1><<<dim3(DM/128, BQ*LK/128), 256, 0, stream>>>(kx, wk, bkv, ck, kws, 12, 1.0f);
    gemm_mfma<3><<<dim3(DM/128, BQ*LK/128), 256, 0, stream>>>(vx, wv, bvv, nullptr, vtb, 12, 1.0f);
    attn_mfma<<<dim3((LQ/QB) * BH * KVS), 256, 0, stream>>>(qws, kws, vtb, op, mlb);
    combine<<<BH*LQ*12/256, 256, 0, stream>>>(op, mlb, ctx);
    gemm_mfma<0><<<dim3(DM/128, BQ*LQ/128), 256, 0, stream>>>(ctx, wo, bov, nullptr, out, 0, 1.0f);
}

// Round 7
// 228.302 us; speedup vs baseline: 9.5036x; 1.0503x over previous
//
#include <hip/hip_runtime.h>
#include <math.h>

#define DM 768
#define NH 8
#define HD 96
#define BQ 4
#define LQ 1024
#define LK 4096
#define BH (BQ*NH)
#define KVS 2              // kv-split factor
#define KC (LK/KVS)        // keys per chunk
#define NT (KC/64)         // 64-key tiles per block

typedef unsigned short ushort;
typedef unsigned int uint;
typedef __attribute__((ext_vector_type(8))) short short8v;
typedef __attribute__((ext_vector_type(4))) float float4v;

// 1/sqrt(96) * log2(e)  (folded into Q projection)
#define QSCALE 0.14724444641f

static __device__ __forceinline__ ushort f2bf(float x) {
    union { float f; uint u; } c; c.f = x;
    uint u = c.u;
    u += ((u >> 16) & 1u) + 0x7fffu;   // RNE
    return (ushort)(u >> 16);
}

static __device__ __forceinline__ uint cvtpk(float lo, float hi) {
    uint d;
    asm("v_cvt_pk_bf16_f32 %0, %1, %2" : "=v"(d) : "v"(lo), "v"(hi));
    return d;
}

static __device__ __forceinline__ float exp2hw(float x) {
#if __has_builtin(__builtin_amdgcn_exp2f)
    return __builtin_amdgcn_exp2f(x);
#else
    return __expf(x * 0.6931471805599453f);
#endif
}

static __device__ __forceinline__ void gload_lds16(const ushort* g, ushort* l) {
    __builtin_amdgcn_global_load_lds(
        (const __attribute__((address_space(1))) uint*)g,
        (__attribute__((address_space(3))) uint*)l, 16, 0, 0);
}

// single fused fp32 -> bf16 converter: 7 segments, 4 elems/thread
__global__ __launch_bounds__(256)
void cvt_all(const float* s0, ushort* d0, int e0,
             const float* s1, ushort* d1, int e1,
             const float* s2, ushort* d2, int e2,
             const float* s3, ushort* d3, int e3,
             const float* s4, ushort* d4, int e4,
             const float* s5, ushort* d5, int e5,
             const float* s6, ushort* d6)
{
    int b = blockIdx.x;
    const float* s; ushort* d; int base;
    if      (b < e0) { s = s0; d = d0; base = 0;  }
    else if (b < e1) { s = s1; d = d1; base = e0; }
    else if (b < e2) { s = s2; d = d2; base = e1; }
    else if (b < e3) { s = s3; d = d3; base = e2; }
    else if (b < e4) { s = s4; d = d4; base = e3; }
    else if (b < e5) { s = s5; d = d5; base = e4; }
    else             { s = s6; d = d6; base = e5; }
    int i = (b - base) * 256 + threadIdx.x;
    float4 v = ((const float4*)s)[i];
    uint2 o;
    o.x = (uint)f2bf(v.x) | ((uint)f2bf(v.y) << 16);
    o.y = (uint)f2bf(v.z) | ((uint)f2bf(v.w) << 16);
    ((uint2*)d)[i] = o;
}

// bf16 MFMA GEMM: C = X @ W^T + b, 128x128xBK64, 1-D grid with XCD row-affinity:
// all 6 col-panels of a row-panel land on one XCD -> A-panel fetched once/XCD.
// MODE 0: fp32 row-major. MODE 1: RoPE (+oscale) + bf16 (B,H,L,96). MODE 2: bf16 (B,H,L,96).
// MODE 3: bf16 V^T (B,H,96,LK) via LDS re-transpose of the C tile.
template<int MODE>
__global__ __launch_bounds__(256)
void gemm_mfma(const ushort* __restrict__ X, const ushort* __restrict__ Wb,
               const float* __restrict__ bias, const float* __restrict__ coords,
               void* __restrict__ out, int Lshift, float oscale, int rpx)
{
    __shared__ ushort Sh[16384];     // As = Sh[0:8192], Bs = Sh[8192:16384]
    ushort* As = Sh;
    ushort* Bs = Sh + 8192;

    const int tid  = threadIdx.x;
    const int w    = tid >> 6;
    const int lane = tid & 63;
    const int l15  = lane & 15;
    const int lg   = lane >> 4;
    const int wm   = w >> 1, wn = w & 1;

    // XCD row-affinity decode
    const int L   = blockIdx.x;
    const int xcd = L & 7;
    const int sq  = L >> 3;
    const int col0 = (sq % 6) * 128;
    const int row0 = (xcd * rpx + sq / 6) * 128;

    float4v acc[4][4];
    #pragma unroll
    for (int m = 0; m < 4; ++m)
        #pragma unroll
        for (int n = 0; n < 4; ++n) acc[m][n] = (float4v)0.f;

    int Pp[4], rrS[4], cbS[4];
    #pragma unroll
    for (int c = 0; c < 4; ++c) {
        int P = ((w*4 + c) << 10) + lane*16;
        int lgc = P ^ (((P >> 9) & 3) << 5);
        Pp[c]  = P;
        rrS[c] = lgc >> 7;
        cbS[c] = (lgc & 127) >> 1;
    }
    const ushort* xb = X  + (size_t)row0 * DM;
    const ushort* wb = Wb + (size_t)col0 * DM;

    int offA[2][4], offB[2][4];
    #pragma unroll
    for (int kk = 0; kk < 2; ++kk) {
        #pragma unroll
        for (int m = 0; m < 4; ++m) {
            int byte = (wm*64 + m*16 + l15)*128 + kk*64 + lg*16;
            offA[kk][m] = byte ^ (((byte >> 9) & 3) << 5);
            byte = (wn*64 + m*16 + l15)*128 + kk*64 + lg*16;
            offB[kk][m] = byte ^ (((byte >> 9) & 3) << 5);
        }
    }

    for (int kt = 0; kt < DM; kt += 64) {
        #pragma unroll
        for (int c = 0; c < 4; ++c) {
            gload_lds16(xb + (size_t)rrS[c]*DM + kt + cbS[c], (ushort*)((char*)As + Pp[c]));
            gload_lds16(wb + (size_t)rrS[c]*DM + kt + cbS[c], (ushort*)((char*)Bs + Pp[c]));
        }
        __syncthreads();
        #pragma unroll
        for (int kk = 0; kk < 2; ++kk) {
            short8v af[4], bfm[4];
            #pragma unroll
            for (int m = 0; m < 4; ++m)
                af[m] = *(const short8v*)((const char*)As + offA[kk][m]);
            #pragma unroll
            for (int n = 0; n < 4; ++n)
                bfm[n] = *(const short8v*)((const char*)Bs + offB[kk][n]);
            #pragma unroll
            for (int m = 0; m < 4; ++m)
                #pragma unroll
                for (int n = 0; n < 4; ++n)
                    acc[m][n] = __builtin_amdgcn_mfma_f32_16x16x32_bf16(af[m], bfm[n], acc[m][n], 0, 0, 0);
        }
        __syncthreads();
    }

    const int colbase = col0 + wn*64;
    float bv[4];
    #pragma unroll
    for (int nt = 0; nt < 4; ++nt) bv[nt] = bias[colbase + nt*16 + l15];
    #pragma unroll
    for (int m = 0; m < 4; ++m)
        #pragma unroll
        for (int nt = 0; nt < 4; ++nt)
            #pragma unroll
            for (int r = 0; r < 4; ++r) acc[m][nt][r] += bv[nt];

    if (MODE == 1) {
        const float freq = exp2f(-(float)l15 * 0.83048202372184058696f);
        const int a0 = ((colbase >> 5) + 0) % 3;
        const int a1 = ((colbase >> 5) + 1) % 3;
        const int F  = (colbase >> 4) & 1;
        #pragma unroll
        for (int m = 0; m < 4; ++m) {
            #pragma unroll
            for (int r = 0; r < 4; ++r) {
                int row = row0 + wm*64 + m*16 + lg*4 + r;
                const float* c3 = coords + (size_t)row * 3;
                float sn0, cs0, sn1, cs1;
                __sincosf(c3[a0] * freq, &sn0, &cs0);
                __sincosf(c3[a1] * freq, &sn1, &cs1);
                {
                    float A_ = F ? acc[m][1][r] : acc[m][0][r];
                    float B_ = F ? acc[m][0][r] : acc[m][1][r];
                    float x1 = (A_*cs0 - B_*sn0) * oscale, x2 = (A_*sn0 + B_*cs0) * oscale;
                    if (F) { acc[m][1][r] = x1; acc[m][0][r] = x2; }
                    else   { acc[m][0][r] = x1; acc[m][1][r] = x2; }
                }
                {
                    float A_ = F ? acc[m][3][r] : acc[m][2][r];
                    float B_ = F ? acc[m][2][r] : acc[m][3][r];
                    float x1 = (A_*cs1 - B_*sn1) * oscale, x2 = (A_*sn1 + B_*cs1) * oscale;
                    if (F) { acc[m][3][r] = x1; acc[m][2][r] = x2; }
                    else   { acc[m][2][r] = x1; acc[m][3][r] = x2; }
                }
            }
        }
    }

    if (MODE == 0) {
        float* o32 = (float*)out;
        #pragma unroll
        for (int m = 0; m < 4; ++m)
            #pragma unroll
            for (int r = 0; r < 4; ++r) {
                int row = row0 + wm*64 + m*16 + lg*4 + r;
                #pragma unroll
                for (int nt = 0; nt < 4; ++nt)
                    o32[(size_t)row*DM + colbase + nt*16 + l15] = acc[m][nt][r];
            }
    } else if (MODE == 3) {
        // re-transpose through LDS (Sh is dead): Cs[col][row] XOR-swizzled
        #pragma unroll
        for (int m = 0; m < 4; ++m)
            #pragma unroll
            for (int nt = 0; nt < 4; ++nt)
                #pragma unroll
                for (int r = 0; r < 4; ++r) {
                    int c  = wn*64 + nt*16 + l15;
                    int ri = wm*64 + m*16 + lg*4 + r;
                    *(ushort*)((char*)Sh + c*256 + (((ri>>3) ^ (c&7))<<4) + (ri&7)*2)
                        = f2bf(acc[m][nt][r]);
                }
        __syncthreads();
        ushort* o16 = (ushort*)out;
        #pragma unroll
        for (int e = 0; e < 8; ++e) {
            int idx = tid + 256*e;
            int c = idx >> 4, r8 = idx & 15;
            uint4 val = *(const uint4*)((const char*)Sh + c*256 + ((r8 ^ (c&7))<<4));
            int j = col0 + c;
            int h = j / HD, t = j % HD;
            int row = row0 + r8*8;
            int b = row >> 12, l = row & (LK-1);
            *(uint4*)&o16[(((size_t)b*NH + h)*HD + t)*LK + l] = val;
        }
    } else {
        ushort* o16 = (ushort*)out;
        const int Lm1 = (1 << Lshift) - 1;
        int hh[4], tt[4];
        #pragma unroll
        for (int nt = 0; nt < 4; ++nt) {
            int j0 = colbase + nt*16;
            hh[nt] = j0 / HD;
            tt[nt] = j0 % HD + l15;
        }
        #pragma unroll
        for (int m = 0; m < 4; ++m)
            #pragma unroll
            for (int r = 0; r < 4; ++r) {
                int row = row0 + wm*64 + m*16 + lg*4 + r;
                int b = row >> Lshift, l = row & Lm1;
                #pragma unroll
                for (int nt = 0; nt < 4; ++nt)
                    o16[(((size_t)b*NH + hh[nt]) << Lshift | l) * HD + tt[nt]] =
                        f2bf(acc[m][nt][r]);
            }
    }
}

// MFMA flash attention, KV-split, swapped-QK^T, exp2-domain softmax.
// Block = 2 waves x 64 q-rows (wave owns 32 = 2 fragments); KVBLK=64.
// Grid 1024 = 4 blocks/CU: independent blocks fill each other's barrier stalls.
// XCD decode: all 16 qt-blocks of one (bh,sc) land on one XCD (K/V L2-resident).
__global__ __launch_bounds__(128, 2)
void attn_mfma(const ushort* __restrict__ q, const ushort* __restrict__ k,
               const ushort* __restrict__ vt, float* __restrict__ op,
               float* __restrict__ mlb)
{
    __shared__ ushort Ks[64*128];     // 16 KB, slot^=(row&7)
    __shared__ ushort Vs[96*64];      // 12 KB, slot^=(row&7)
    __shared__ ushort PsT[2][32][72]; // 9 KB: [wave][q][key]

    const int tid  = threadIdx.x;
    const int w    = tid >> 6;
    const int lane = tid & 63;
    const int l15  = lane & 15;
    const int lg   = lane >> 4;

    // decode: same (bh,sc) -> same XCD; qt sequential within XCD
    const int L   = blockIdx.x;
    const int xcd = L & 7;
    const int s   = L >> 3;                 // 0..127
    const int pr  = xcd*8 + (s >> 4);       // 0..63
    const int qt  = s & 15;                 // 0..15
    const int bh  = pr & 31;
    const int sc  = pr >> 5;

    const ushort* qg = q  + ((size_t)bh * LQ + qt*64 + w*32 + l15) * HD;
    const ushort* kg = k  + ((size_t)bh * LK + (size_t)sc * KC) * HD;
    const ushort* vg = vt + (size_t)bh * HD * LK + (size_t)sc * KC;

    short8v aq0[3], aq1[3];
    #pragma unroll
    for (int dc = 0; dc < 3; ++dc) {
        aq0[dc] = *(const short8v*)(qg + dc*32 + lg*8);
        aq1[dc] = *(const short8v*)(qg + 16*HD + dc*32 + lg*8);
    }

    // staging geometry: 6 K-chunks + 6 V-chunks per thread (128 thr x 6 = 768)
    int kdst[6], ksrc[6], vdst[6], vsrc[6];
    #pragma unroll
    for (int j = 0; j < 6; ++j) {
        int c = tid + 128*j;
        int kr = c / 12, ks = c % 12;
        kdst[j] = kr*256 + ((ks ^ (kr & 7)) << 4);
        ksrc[j] = kr*HD + ks*8;
        int vr = c >> 3, vs = c & 7;
        vdst[j] = vr*128 + ((vs ^ (vr & 7)) << 4);
        vsrc[j] = vr*LK + vs*8;
    }
    int tK[3], tV[2];
    #pragma unroll
    for (int dc = 0; dc < 3; ++dc) tK[dc] = ((dc*4 + lg) ^ (l15 & 7)) << 4;
    #pragma unroll
    for (int h2 = 0; h2 < 2; ++h2)  tV[h2] = ((h2*4 + lg) ^ (l15 & 7)) << 4;

    float4v o0[6], o1[6];
    #pragma unroll
    for (int dt = 0; dt < 6; ++dt) { o0[dt] = (float4v)0.f; o1[dt] = (float4v)0.f; }
    float m_0 = -1e30f, l_0 = 0.f;   // q = l15       (log2 domain)
    float m_1 = -1e30f, l_1 = 0.f;   // q = 16 + l15

    short8v kreg[6], vreg[6];
    #pragma unroll
    for (int j = 0; j < 6; ++j) {
        kreg[j] = *(const short8v*)(kg + ksrc[j]);
        vreg[j] = *(const short8v*)(vg + vsrc[j]);
    }
    #pragma unroll
    for (int j = 0; j < 6; ++j) {
        *(short8v*)((char*)Ks + kdst[j]) = kreg[j];
        *(short8v*)((char*)Vs + vdst[j]) = vreg[j];
    }
    __syncthreads();

    for (int t = 0; t < NT; ++t) {
        if (t + 1 < NT) {
            const ushort* kn = kg + (size_t)(t+1)*64*HD;
            const ushort* vn = vg + (t+1)*64;
            #pragma unroll
            for (int j = 0; j < 6; ++j) {
                kreg[j] = *(const short8v*)(kn + ksrc[j]);
                vreg[j] = *(const short8v*)(vn + vsrc[j]);
            }
        }

        // ---- S^T = K Q^T : lane holds q=l15 (frag0) / 16+l15 (frag1) ----
        float4v s0[4], s1[4];
        __builtin_amdgcn_s_setprio(1);
        #pragma unroll
        for (int nt = 0; nt < 4; ++nt) {
            s0[nt] = (float4v)0.f;
            s1[nt] = (float4v)0.f;
            #pragma unroll
            for (int dc = 0; dc < 3; ++dc) {
                short8v bk = *(const short8v*)((const char*)Ks + nt*4096 + l15*256 + tK[dc]);
                s0[nt] = __builtin_amdgcn_mfma_f32_16x16x32_bf16(bk, aq0[dc], s0[nt], 0, 0, 0);
                s1[nt] = __builtin_amdgcn_mfma_f32_16x16x32_bf16(bk, aq1[dc], s1[nt], 0, 0, 0);
            }
        }
        __builtin_amdgcn_s_setprio(0);

        // ---- online softmax (log2 domain) ----
        float mt0 = -1e30f, mt1 = -1e30f;
        #pragma unroll
        for (int nt = 0; nt < 4; ++nt)
            #pragma unroll
            for (int r = 0; r < 4; ++r) {
                mt0 = fmaxf(mt0, s0[nt][r]);
                mt1 = fmaxf(mt1, s1[nt][r]);
            }
        mt0 = fmaxf(mt0, __shfl_xor(mt0, 16, 64));
        mt0 = fmaxf(mt0, __shfl_xor(mt0, 32, 64));
        mt1 = fmaxf(mt1, __shfl_xor(mt1, 16, 64));
        mt1 = fmaxf(mt1, __shfl_xor(mt1, 32, 64));

        if (__any((mt0 > m_0 + 11.5f) || (mt1 > m_1 + 11.5f))) {
            float mn0 = fmaxf(m_0, mt0), mn1 = fmaxf(m_1, mt1);
            float a0 = exp2hw(m_0 - mn0), a1 = exp2hw(m_1 - mn1);
            m_0 = mn0; m_1 = mn1;
            l_0 *= a0;  l_1 *= a1;
            float al0[4], al1[4];
            #pragma unroll
            for (int r = 0; r < 4; ++r) {
                al0[r] = __shfl(a0, lg*4 + r, 64);
                al1[r] = __shfl(a1, lg*4 + r, 64);
            }
            #pragma unroll
            for (int dt = 0; dt < 6; ++dt)
                #pragma unroll
                for (int r = 0; r < 4; ++r) {
                    o0[dt][r] *= al0[r];
                    o1[dt][r] *= al1[r];
                }
        }

        float ps0 = 0.f, ps1 = 0.f;
        #pragma unroll
        for (int nt = 0; nt < 4; ++nt)
            #pragma unroll
            for (int r = 0; r < 4; ++r) {
                float p0 = exp2hw(s0[nt][r] - m_0);
                float p1 = exp2hw(s1[nt][r] - m_1);
                s0[nt][r] = p0; ps0 += p0;
                s1[nt][r] = p1; ps1 += p1;
            }
        ps0 += __shfl_xor(ps0, 16, 64);
        ps0 += __shfl_xor(ps0, 32, 64);
        ps1 += __shfl_xor(ps1, 16, 64);
        ps1 += __shfl_xor(ps1, 32, 64);
        l_0 += ps0;
        l_1 += ps1;

        // ---- pack P^T rows ----
        #pragma unroll
        for (int nt = 0; nt < 4; ++nt) {
            uint2 pk0, pk1;
            pk0.x = cvtpk(s0[nt][0], s0[nt][1]);
            pk0.y = cvtpk(s0[nt][2], s0[nt][3]);
            pk1.x = cvtpk(s1[nt][0], s1[nt][1]);
            pk1.y = cvtpk(s1[nt][2], s1[nt][3]);
            *(uint2*)&PsT[w][l15][nt*16 + lg*4]      = pk0;
            *(uint2*)&PsT[w][16 + l15][nt*16 + lg*4] = pk1;
        }

        // ---- O += P V  (Vs fragments shared between both q-frags) ----
        short8v a00 = *(const short8v*)&PsT[w][l15][lg*8];
        short8v a01 = *(const short8v*)&PsT[w][l15][32 + lg*8];
        short8v a10 = *(const short8v*)&PsT[w][16 + l15][lg*8];
        short8v a11 = *(const short8v*)&PsT[w][16 + l15][32 + lg*8];
        __builtin_amdgcn_s_setprio(1);
        #pragma unroll
        for (int dt = 0; dt < 6; ++dt) {
            short8v bv0 = *(const short8v*)((const char*)Vs + dt*2048 + l15*128 + tV[0]);
            short8v bv1 = *(const short8v*)((const char*)Vs + dt*2048 + l15*128 + tV[1]);
            o0[dt] = __builtin_amdgcn_mfma_f32_16x16x32_bf16(a00, bv0, o0[dt], 0, 0, 0);
            o0[dt] = __builtin_amdgcn_mfma_f32_16x16x32_bf16(a01, bv1, o0[dt], 0, 0, 0);
            o1[dt] = __builtin_amdgcn_mfma_f32_16x16x32_bf16(a10, bv0, o1[dt], 0, 0, 0);
            o1[dt] = __builtin_amdgcn_mfma_f32_16x16x32_bf16(a11, bv1, o1[dt], 0, 0, 0);
        }
        __builtin_amdgcn_s_setprio(0);
        __syncthreads();

        if (t + 1 < NT) {
            #pragma unroll
            for (int j = 0; j < 6; ++j) {
                *(short8v*)((char*)Ks + kdst[j]) = kreg[j];
                *(short8v*)((char*)Vs + vdst[j]) = vreg[j];
            }
        }
        __syncthreads();
    }

    // ---- epilogue: unnormalized partials ----
    float* ob = op + (((size_t)sc * BH + bh) * LQ + qt*64 + w*32) * HD;
    #pragma unroll
    for (int r = 0; r < 4; ++r) {
        #pragma unroll
        for (int dt = 0; dt < 6; ++dt) {
            ob[(size_t)(lg*4 + r) * HD + dt*16 + l15]      = o0[dt][r];
            ob[(size_t)(16 + lg*4 + r) * HD + dt*16 + l15] = o1[dt][r];
        }
    }
    if (lane < 16) {
        size_t mlrow = ((size_t)sc * BH + bh) * LQ + qt*64 + w*32 + lane;
        mlb[mlrow*2 + 0] = m_0;
        mlb[mlrow*2 + 1] = l_0;
        mlb[(mlrow + 16)*2 + 0] = m_1;
        mlb[(mlrow + 16)*2 + 1] = l_1;
    }
}

// merge KVS=2 partials -> ctx bf16 (B, LQ, 768); m,l in log2 domain
__global__ __launch_bounds__(256)
void combine(const float* __restrict__ op, const float* __restrict__ mlb,
             ushort* __restrict__ ctx)
{
    const int NROW = BH * LQ;
    int idx = blockIdx.x * 256 + threadIdx.x;
    int row = idx / 12, seg = idx % 12;
    float m0 = mlb[(size_t)row*2],          l0 = mlb[(size_t)row*2 + 1];
    float m1 = mlb[(size_t)(NROW + row)*2], l1 = mlb[(size_t)(NROW + row)*2 + 1];
    float ms = fmaxf(m0, m1);
    float w0 = exp2hw(m0 - ms), w1 = exp2hw(m1 - ms);
    float inv = 1.f / (l0*w0 + l1*w1);
    const float4* p0 = (const float4*)(op + (size_t)row*HD + seg*8);
    const float4* p1 = (const float4*)(op + (size_t)(NROW + row)*HD + seg*8);
    float4 a0 = p0[0], a1 = p0[1];
    float4 b0 = p1[0], b1 = p1[1];
    float r0 = (a0.x*w0 + b0.x*w1)*inv, r1 = (a0.y*w0 + b0.y*w1)*inv;
    float r2 = (a0.z*w0 + b0.z*w1)*inv, r3 = (a0.w*w0 + b0.w*w1)*inv;
    float r4 = (a1.x*w0 + b1.x*w1)*inv, r5 = (a1.y*w0 + b1.y*w1)*inv;
    float r6 = (a1.z*w0 + b1.z*w1)*inv, r7 = (a1.w*w0 + b1.w*w1)*inv;
    int bh = row / LQ, l = row % LQ;
    int b = bh >> 3, h = bh & 7;
    ushort* o = ctx + ((size_t)b * LQ + l) * DM + h * HD + seg*8;
    uint4 pk;
    pk.x = (uint)f2bf(r0) | ((uint)f2bf(r1) << 16);
    pk.y = (uint)f2bf(r2) | ((uint)f2bf(r3) << 16);
    pk.z = (uint)f2bf(r4) | ((uint)f2bf(r5) << 16);
    pk.w = (uint)f2bf(r6) | ((uint)f2bf(r7) << 16);
    *(uint4*)o = pk;
}

extern "C" void kernel_launch(void* const* d_in, const int* in_sizes, int n_in,
                              void* d_out, int out_size, void* d_ws, size_t ws_size,
                              hipStream_t stream)
{
    const float* query = (const float*)d_in[0];
    const float* key   = (const float*)d_in[1];
    const float* value = (const float*)d_in[2];
    const float* cq    = (const float*)d_in[3];
    const float* ck    = (const float*)d_in[4];
    const float* Wq    = (const float*)d_in[5];
    const float* bqv   = (const float*)d_in[6];
    const float* Wk    = (const float*)d_in[7];
    const float* bkv   = (const float*)d_in[8];
    const float* Wv    = (const float*)d_in[9];
    const float* bvv   = (const float*)d_in[10];
    const float* Wo    = (const float*)d_in[11];
    const float* bov   = (const float*)d_in[12];
    float* out = (float*)d_out;

    const size_t NQ = (size_t)BQ * LQ * DM;   // 3,145,728
    const size_t NK = (size_t)BQ * LK * DM;   // 12,582,912
    const size_t NW = (size_t)DM * DM;        //    589,824

    ushort* qx  = (ushort*)d_ws;
    ushort* kx  = qx  + NQ;
    ushort* vx  = kx  + NK;
    ushort* wq  = vx  + NK;
    ushort* wk  = wq  + NW;
    ushort* wv  = wk  + NW;
    ushort* wo  = wv  + NW;
    ushort* qws = wo  + NW;
    ushort* kws = qws + NQ;
    ushort* vws = kws + NK;
    ushort* vtb = kx;                 // overlays kx (dead after gemm_k)
    ushort* ctx = qx;                 // overlays qx (dead after gemm_q)
    float*  op  = (float*)vws;        // partial O: KVS*BH*LQ*HD fp32 = 25 MB
    float*  mlb = (float*)vx;         // overlays vx (dead after gemm_v)

    // fused converter: segments in blocks of 1024 floats
    const int e0 = (int)(NQ/1024);            // 3072   query
    const int e1 = e0 + (int)(NK/1024);       // 15360  key
    const int e2 = e1 + (int)(NK/1024);       // 27648  value
    const int e3 = e2 + (int)(NW/1024);       // 28224  Wq
    const int e4 = e3 + (int)(NW/1024);       // 28800  Wk
    const int e5 = e4 + (int)(NW/1024);       // 29376  Wv
    const int e6 = e5 + (int)(NW/1024);       // 29952  Wo
    cvt_all<<<e6, 256, 0, stream>>>(query, qx, e0, key, kx, e1, value, vx, e2,
                                    Wq, wq, e3, Wk, wk, e4, Wv, wv, e5, Wo, wo);

    gemm_mfma<1><<<(BQ*LQ/128)*6, 256, 0, stream>>>(qx, wq, bqv, cq, qws, 10, QSCALE, (BQ*LQ/128)/8);
    gemm_mfma<1><<<(BQ*LK/128)*6, 256, 0, stream>>>(kx, wk, bkv, ck, kws, 12, 1.0f, (BQ*LK/128)/8);
    gemm_mfma<3><<<(BQ*LK/128)*6, 256, 0, stream>>>(vx, wv, bvv, nullptr, vtb, 12, 1.0f, (BQ*LK/128)/8);
    attn_mfma<<<(LQ/64) * BH * KVS, 128, 0, stream>>>(qws, kws, vtb, op, mlb);
    combine<<<BH*LQ*12/256, 256, 0, stream>>>(op, mlb, ctx);
    gemm_mfma<0><<<(BQ*LQ/128)*6, 256, 0, stream>>>(ctx, wo, bov, nullptr, out, 0, 1.0f, (BQ*LQ/128)/8);
}

// Round 8
// 171.123 us; speedup vs baseline: 12.6791x; 1.3341x over previous
//
#include <hip/hip_runtime.h>
#include <math.h>

#define DM 768
#define NH 8
#define HD 96
#define BQ 4
#define LQ 1024
#define LK 4096
#define BH (BQ*NH)
#define KVS 4              // kv-split factor
#define KC (LK/KVS)        // keys per chunk = 1024
#define NT (KC/64)         // 64-key tiles per block = 16
#define QB 128             // q-rows per block (32 per wave)
#define NW (DM*DM)

typedef unsigned short ushort;
typedef unsigned int uint;
typedef __attribute__((ext_vector_type(8))) short short8v;
typedef __attribute__((ext_vector_type(4))) float float4v;

// 1/sqrt(96) * log2(e)  (folded into Q projection)
#define QSCALE 0.14724444641f

static __device__ __forceinline__ ushort f2bf(float x) {
    union { float f; uint u; } c; c.f = x;
    uint u = c.u;
    u += ((u >> 16) & 1u) + 0x7fffu;   // RNE
    return (ushort)(u >> 16);
}

static __device__ __forceinline__ float bf2f(ushort x) {
    union { uint u; float f; } c; c.u = (uint)x << 16;
    return c.f;
}

static __device__ __forceinline__ uint cvtpk(float lo, float hi) {
    uint d;
    asm("v_cvt_pk_bf16_f32 %0, %1, %2" : "=v"(d) : "v"(lo), "v"(hi));
    return d;
}

static __device__ __forceinline__ float exp2hw(float x) {
#if __has_builtin(__builtin_amdgcn_exp2f)
    return __builtin_amdgcn_exp2f(x);
#else
    return __expf(x * 0.6931471805599453f);
#endif
}

static __device__ __forceinline__ void gload_lds16(const ushort* g, ushort* l) {
    __builtin_amdgcn_global_load_lds(
        (const __attribute__((address_space(1))) uint*)g,
        (__attribute__((address_space(3))) uint*)l, 16, 0, 0);
}

// weights fp32 -> bf16 (4 matrices into contiguous dst), 4 elems/thread
__global__ __launch_bounds__(256)
void wcvt(const float* __restrict__ w0, const float* __restrict__ w1,
          const float* __restrict__ w2, const float* __restrict__ w3,
          ushort* __restrict__ d)
{
    const int SEG = NW / 1024;           // 576 blocks per matrix
    int b = blockIdx.x;
    int wsel = b / SEG, ib = b % SEG;
    const float* s = (wsel == 0) ? w0 : (wsel == 1) ? w1 : (wsel == 2) ? w2 : w3;
    int i = ib * 256 + threadIdx.x;
    float4 v = ((const float4*)s)[i];
    uint2 o;
    o.x = (uint)f2bf(v.x) | ((uint)f2bf(v.y) << 16);
    o.y = (uint)f2bf(v.z) | ((uint)f2bf(v.w) << 16);
    ((uint2*)(d + (size_t)wsel * NW))[i] = o;
}

// Fused QKV projection GEMM, fp32 A-input (cvt fused into staging), bf16 weights.
// Segments: blocks [0,192) = Q (RoPE, Lshift=10), [192,960) = K (RoPE, 12),
// [960,1728) = V (transpose epilogue -> (B,H,96,LK)).
// XCD row-affinity within each segment (bases are multiples of 8).
__global__ __launch_bounds__(256, 2)
void qkv_gemm(const float* __restrict__ qf, const float* __restrict__ kf,
              const float* __restrict__ vf,
              const ushort* __restrict__ wqb, const ushort* __restrict__ wkb,
              const ushort* __restrict__ wvb,
              const float* __restrict__ bq, const float* __restrict__ bk,
              const float* __restrict__ bv,
              const float* __restrict__ cq, const float* __restrict__ ck,
              ushort* __restrict__ qws, ushort* __restrict__ kws,
              ushort* __restrict__ vtb)
{
    __shared__ ushort Sh[16384];     // As = [0:8192], Bs = [8192:16384]
    ushort* As = Sh;
    ushort* Bs = Sh + 8192;

    const int tid  = threadIdx.x;
    const int w    = tid >> 6;
    const int lane = tid & 63;
    const int l15  = lane & 15;
    const int lg   = lane >> 4;
    const int wm   = w >> 1, wn = w & 1;

    // segment decode (block-uniform)
    const int L = blockIdx.x;
    int seg, idx, Lshift, rpx;
    const float* X32; const ushort* Wbp; const float* bias; const float* coords;
    ushort* out; float oscale;
    if (L < 192)      { seg = 0; idx = L;       X32 = qf; Wbp = wqb; bias = bq; coords = cq; out = qws; Lshift = 10; rpx = 4;  oscale = QSCALE; }
    else if (L < 960) { seg = 1; idx = L - 192; X32 = kf; Wbp = wkb; bias = bk; coords = ck; out = kws; Lshift = 12; rpx = 16; oscale = 1.0f; }
    else              { seg = 2; idx = L - 960; X32 = vf; Wbp = wvb; bias = bv; coords = 0;  out = vtb; Lshift = 12; rpx = 16; oscale = 1.0f; }

    const int xcd  = idx & 7;
    const int sq   = idx >> 3;
    const int col0 = (sq % 6) * 128;
    const int row0 = (xcd * rpx + sq / 6) * 128;

    float4v acc[4][4];
    #pragma unroll
    for (int m = 0; m < 4; ++m)
        #pragma unroll
        for (int n = 0; n < 4; ++n) acc[m][n] = (float4v)0.f;

    int Pp[4], rrS[4], cbS[4];
    #pragma unroll
    for (int c = 0; c < 4; ++c) {
        int P = ((w*4 + c) << 10) + lane*16;
        int lgc = P ^ (((P >> 9) & 3) << 5);
        Pp[c]  = P;
        rrS[c] = lgc >> 7;
        cbS[c] = (lgc & 127) >> 1;
    }
    const float*  xb = X32 + (size_t)row0 * DM;
    const ushort* wb = Wbp + (size_t)col0 * DM;

    int offA[2][4], offB[2][4];
    #pragma unroll
    for (int kk = 0; kk < 2; ++kk) {
        #pragma unroll
        for (int m = 0; m < 4; ++m) {
            int byte = (wm*64 + m*16 + l15)*128 + kk*64 + lg*16;
            offA[kk][m] = byte ^ (((byte >> 9) & 3) << 5);
            byte = (wn*64 + m*16 + l15)*128 + kk*64 + lg*16;
            offB[kk][m] = byte ^ (((byte >> 9) & 3) << 5);
        }
    }

    for (int kt = 0; kt < DM; kt += 64) {
        // A: fp32 reg-stage + cvt + ds_write (fused conversion)
        float4 fa[4], fb[4];
        #pragma unroll
        for (int c = 0; c < 4; ++c) {
            const float* src = xb + (size_t)rrS[c]*DM + kt + cbS[c];
            fa[c] = *(const float4*)src;
            fb[c] = *(const float4*)(src + 4);
        }
        // B: async global->LDS (bf16)
        #pragma unroll
        for (int c = 0; c < 4; ++c)
            gload_lds16(wb + (size_t)rrS[c]*DM + kt + cbS[c], (ushort*)((char*)Bs + Pp[c]));
        #pragma unroll
        for (int c = 0; c < 4; ++c) {
            uint4 pk;
            pk.x = cvtpk(fa[c].x, fa[c].y);
            pk.y = cvtpk(fa[c].z, fa[c].w);
            pk.z = cvtpk(fb[c].x, fb[c].y);
            pk.w = cvtpk(fb[c].z, fb[c].w);
            *(uint4*)((char*)As + Pp[c]) = pk;
        }
        __syncthreads();
        #pragma unroll
        for (int kk = 0; kk < 2; ++kk) {
            short8v af[4], bfm[4];
            #pragma unroll
            for (int m = 0; m < 4; ++m)
                af[m] = *(const short8v*)((const char*)As + offA[kk][m]);
            #pragma unroll
            for (int n = 0; n < 4; ++n)
                bfm[n] = *(const short8v*)((const char*)Bs + offB[kk][n]);
            #pragma unroll
            for (int m = 0; m < 4; ++m)
                #pragma unroll
                for (int n = 0; n < 4; ++n)
                    acc[m][n] = __builtin_amdgcn_mfma_f32_16x16x32_bf16(af[m], bfm[n], acc[m][n], 0, 0, 0);
        }
        __syncthreads();
    }

    const int colbase = col0 + wn*64;
    float bvv[4];
    #pragma unroll
    for (int nt = 0; nt < 4; ++nt) bvv[nt] = bias[colbase + nt*16 + l15];
    #pragma unroll
    for (int m = 0; m < 4; ++m)
        #pragma unroll
        for (int nt = 0; nt < 4; ++nt)
            #pragma unroll
            for (int r = 0; r < 4; ++r) acc[m][nt][r] += bvv[nt];

    if (seg < 2) {
        // RoPE + bf16 (B,NH,L,96) store
        const float freq = exp2f(-(float)l15 * 0.83048202372184058696f);
        const int a0 = ((colbase >> 5) + 0) % 3;
        const int a1 = ((colbase >> 5) + 1) % 3;
        const int F  = (colbase >> 4) & 1;
        #pragma unroll
        for (int m = 0; m < 4; ++m) {
            #pragma unroll
            for (int r = 0; r < 4; ++r) {
                int row = row0 + wm*64 + m*16 + lg*4 + r;
                const float* c3 = coords + (size_t)row * 3;
                float sn0, cs0, sn1, cs1;
                __sincosf(c3[a0] * freq, &sn0, &cs0);
                __sincosf(c3[a1] * freq, &sn1, &cs1);
                {
                    float A_ = F ? acc[m][1][r] : acc[m][0][r];
                    float B_ = F ? acc[m][0][r] : acc[m][1][r];
                    float x1 = (A_*cs0 - B_*sn0) * oscale, x2 = (A_*sn0 + B_*cs0) * oscale;
                    if (F) { acc[m][1][r] = x1; acc[m][0][r] = x2; }
                    else   { acc[m][0][r] = x1; acc[m][1][r] = x2; }
                }
                {
                    float A_ = F ? acc[m][3][r] : acc[m][2][r];
                    float B_ = F ? acc[m][2][r] : acc[m][3][r];
                    float x1 = (A_*cs1 - B_*sn1) * oscale, x2 = (A_*sn1 + B_*cs1) * oscale;
                    if (F) { acc[m][3][r] = x1; acc[m][2][r] = x2; }
                    else   { acc[m][2][r] = x1; acc[m][3][r] = x2; }
                }
            }
        }
        const int Lm1 = (1 << Lshift) - 1;
        int hh[4], tt[4];
        #pragma unroll
        for (int nt = 0; nt < 4; ++nt) {
            int j0 = colbase + nt*16;
            hh[nt] = j0 / HD;
            tt[nt] = j0 % HD + l15;
        }
        #pragma unroll
        for (int m = 0; m < 4; ++m)
            #pragma unroll
            for (int r = 0; r < 4; ++r) {
                int row = row0 + wm*64 + m*16 + lg*4 + r;
                int b = row >> Lshift, l = row & Lm1;
                #pragma unroll
                for (int nt = 0; nt < 4; ++nt)
                    out[(((size_t)b*NH + hh[nt]) << Lshift | l) * HD + tt[nt]] =
                        f2bf(acc[m][nt][r]);
            }
    } else {
        // V: re-transpose through LDS (Sh dead) -> bf16 (B,NH,96,LK)
        #pragma unroll
        for (int m = 0; m < 4; ++m)
            #pragma unroll
            for (int nt = 0; nt < 4; ++nt)
                #pragma unroll
                for (int r = 0; r < 4; ++r) {
                    int c  = wn*64 + nt*16 + l15;
                    int ri = wm*64 + m*16 + lg*4 + r;
                    *(ushort*)((char*)Sh + c*256 + (((ri>>3) ^ (c&7))<<4) + (ri&7)*2)
                        = f2bf(acc[m][nt][r]);
                }
        __syncthreads();
        #pragma unroll
        for (int e = 0; e < 8; ++e) {
            int idx2 = tid + 256*e;
            int c = idx2 >> 4, r8 = idx2 & 15;
            uint4 val = *(const uint4*)((const char*)Sh + c*256 + ((r8 ^ (c&7))<<4));
            int j = col0 + c;
            int h = j / HD, t = j % HD;
            int row = row0 + r8*8;
            int b = row >> 12, l = row & (LK-1);
            *(uint4*)&out[(((size_t)b*NH + h)*HD + t)*LK + l] = val;
        }
    }
}

// Output projection GEMM: ctx bf16 -> out fp32, 128x128xBK64, XCD row-affinity.
__global__ __launch_bounds__(256)
void gemm_out(const ushort* __restrict__ X, const ushort* __restrict__ Wb,
              const float* __restrict__ bias, float* __restrict__ out)
{
    __shared__ ushort Sh[16384];
    ushort* As = Sh;
    ushort* Bs = Sh + 8192;

    const int tid  = threadIdx.x;
    const int w    = tid >> 6;
    const int lane = tid & 63;
    const int l15  = lane & 15;
    const int lg   = lane >> 4;
    const int wm   = w >> 1, wn = w & 1;

    const int L    = blockIdx.x;
    const int xcd  = L & 7;
    const int sq   = L >> 3;
    const int col0 = (sq % 6) * 128;
    const int row0 = (xcd * 4 + sq / 6) * 128;

    float4v acc[4][4];
    #pragma unroll
    for (int m = 0; m < 4; ++m)
        #pragma unroll
        for (int n = 0; n < 4; ++n) acc[m][n] = (float4v)0.f;

    int Pp[4], rrS[4], cbS[4];
    #pragma unroll
    for (int c = 0; c < 4; ++c) {
        int P = ((w*4 + c) << 10) + lane*16;
        int lgc = P ^ (((P >> 9) & 3) << 5);
        Pp[c]  = P;
        rrS[c] = lgc >> 7;
        cbS[c] = (lgc & 127) >> 1;
    }
    const ushort* xb = X  + (size_t)row0 * DM;
    const ushort* wb = Wb + (size_t)col0 * DM;

    int offA[2][4], offB[2][4];
    #pragma unroll
    for (int kk = 0; kk < 2; ++kk) {
        #pragma unroll
        for (int m = 0; m < 4; ++m) {
            int byte = (wm*64 + m*16 + l15)*128 + kk*64 + lg*16;
            offA[kk][m] = byte ^ (((byte >> 9) & 3) << 5);
            byte = (wn*64 + m*16 + l15)*128 + kk*64 + lg*16;
            offB[kk][m] = byte ^ (((byte >> 9) & 3) << 5);
        }
    }

    for (int kt = 0; kt < DM; kt += 64) {
        #pragma unroll
        for (int c = 0; c < 4; ++c) {
            gload_lds16(xb + (size_t)rrS[c]*DM + kt + cbS[c], (ushort*)((char*)As + Pp[c]));
            gload_lds16(wb + (size_t)rrS[c]*DM + kt + cbS[c], (ushort*)((char*)Bs + Pp[c]));
        }
        __syncthreads();
        #pragma unroll
        for (int kk = 0; kk < 2; ++kk) {
            short8v af[4], bfm[4];
            #pragma unroll
            for (int m = 0; m < 4; ++m)
                af[m] = *(const short8v*)((const char*)As + offA[kk][m]);
            #pragma unroll
            for (int n = 0; n < 4; ++n)
                bfm[n] = *(const short8v*)((const char*)Bs + offB[kk][n]);
            #pragma unroll
            for (int m = 0; m < 4; ++m)
                #pragma unroll
                for (int n = 0; n < 4; ++n)
                    acc[m][n] = __builtin_amdgcn_mfma_f32_16x16x32_bf16(af[m], bfm[n], acc[m][n], 0, 0, 0);
        }
        __syncthreads();
    }

    const int colbase = col0 + wn*64;
    float bvv[4];
    #pragma unroll
    for (int nt = 0; nt < 4; ++nt) bvv[nt] = bias[colbase + nt*16 + l15];
    #pragma unroll
    for (int m = 0; m < 4; ++m)
        #pragma unroll
        for (int r = 0; r < 4; ++r) {
            int row = row0 + wm*64 + m*16 + lg*4 + r;
            #pragma unroll
            for (int nt = 0; nt < 4; ++nt)
                out[(size_t)row*DM + colbase + nt*16 + l15] = acc[m][nt][r] + bvv[nt];
        }
}

// MFMA flash attention, KV-split 4, swapped-QK^T, exp2-domain softmax.
// Block = 4 waves x 128 q-rows (wave owns 32 = 2 fragments); KVBLK=64.
// Grid 1024 -> 3 blocks/CU (LDS-capped). XCD decode keeps K/V chunk L2-resident.
// Writes unnormalized partial O (bf16) + per-row m,l (log2 domain).
__global__ __launch_bounds__(256, 2)
void attn_mfma(const ushort* __restrict__ q, const ushort* __restrict__ k,
               const ushort* __restrict__ vt, ushort* __restrict__ opb,
               float* __restrict__ mlb)
{
    __shared__ ushort Ks[64*128];     // 16 KB, slot^=(row&7)
    __shared__ ushort Vs[96*64];      // 12 KB, slot^=(row&7)
    __shared__ ushort PsT[4][32][72]; // 18 KB: [wave][q][key]

    const int tid  = threadIdx.x;
    const int w    = tid >> 6;
    const int lane = tid & 63;
    const int l15  = lane & 15;
    const int lg   = lane >> 4;

    // decode: same (bh,sc) -> same XCD; qt sequential within XCD
    const int L   = blockIdx.x;
    const int xcd = L & 7;
    const int s   = L >> 3;                 // 0..127
    const int pr  = xcd*16 + (s >> 3);      // 0..127
    const int qt  = s & 7;                  // 0..7
    const int bh  = pr & 31;
    const int sc  = pr >> 5;                // 0..3

    const ushort* qg = q  + ((size_t)bh * LQ + qt*QB + w*32 + l15) * HD;
    const ushort* kg = k  + ((size_t)bh * LK + (size_t)sc * KC) * HD;
    const ushort* vg = vt + (size_t)bh * HD * LK + (size_t)sc * KC;

    short8v aq0[3], aq1[3];
    #pragma unroll
    for (int dc = 0; dc < 3; ++dc) {
        aq0[dc] = *(const short8v*)(qg + dc*32 + lg*8);
        aq1[dc] = *(const short8v*)(qg + 16*HD + dc*32 + lg*8);
    }

    int kdst[3], ksrc[3], vdst[3], vsrc[3];
    #pragma unroll
    for (int j = 0; j < 3; ++j) {
        int c = tid + 256*j;
        int kr = c / 12, ks = c % 12;
        kdst[j] = kr*256 + ((ks ^ (kr & 7)) << 4);
        ksrc[j] = kr*HD + ks*8;
        int vr = c >> 3, vs = c & 7;
        vdst[j] = vr*128 + ((vs ^ (vr & 7)) << 4);
        vsrc[j] = vr*LK + vs*8;
    }
    int tK[3], tV[2];
    #pragma unroll
    for (int dc = 0; dc < 3; ++dc) tK[dc] = ((dc*4 + lg) ^ (l15 & 7)) << 4;
    #pragma unroll
    for (int h2 = 0; h2 < 2; ++h2)  tV[h2] = ((h2*4 + lg) ^ (l15 & 7)) << 4;

    float4v o0[6], o1[6];
    #pragma unroll
    for (int dt = 0; dt < 6; ++dt) { o0[dt] = (float4v)0.f; o1[dt] = (float4v)0.f; }
    float m_0 = -1e30f, l_0 = 0.f;
    float m_1 = -1e30f, l_1 = 0.f;

    short8v kreg[3], vreg[3];
    #pragma unroll
    for (int j = 0; j < 3; ++j) {
        kreg[j] = *(const short8v*)(kg + ksrc[j]);
        vreg[j] = *(const short8v*)(vg + vsrc[j]);
    }
    #pragma unroll
    for (int j = 0; j < 3; ++j) {
        *(short8v*)((char*)Ks + kdst[j]) = kreg[j];
        *(short8v*)((char*)Vs + vdst[j]) = vreg[j];
    }
    __syncthreads();

    for (int t = 0; t < NT; ++t) {
        if (t + 1 < NT) {
            const ushort* kn = kg + (size_t)(t+1)*64*HD;
            const ushort* vn = vg + (t+1)*64;
            #pragma unroll
            for (int j = 0; j < 3; ++j) {
                kreg[j] = *(const short8v*)(kn + ksrc[j]);
                vreg[j] = *(const short8v*)(vn + vsrc[j]);
            }
        }

        // ---- S^T = K Q^T ----
        float4v s0[4], s1[4];
        __builtin_amdgcn_s_setprio(1);
        #pragma unroll
        for (int nt = 0; nt < 4; ++nt) {
            s0[nt] = (float4v)0.f;
            s1[nt] = (float4v)0.f;
            #pragma unroll
            for (int dc = 0; dc < 3; ++dc) {
                short8v bk = *(const short8v*)((const char*)Ks + nt*4096 + l15*256 + tK[dc]);
                s0[nt] = __builtin_amdgcn_mfma_f32_16x16x32_bf16(bk, aq0[dc], s0[nt], 0, 0, 0);
                s1[nt] = __builtin_amdgcn_mfma_f32_16x16x32_bf16(bk, aq1[dc], s1[nt], 0, 0, 0);
            }
        }
        __builtin_amdgcn_s_setprio(0);

        // ---- online softmax (log2 domain) ----
        float mt0 = -1e30f, mt1 = -1e30f;
        #pragma unroll
        for (int nt = 0; nt < 4; ++nt)
            #pragma unroll
            for (int r = 0; r < 4; ++r) {
                mt0 = fmaxf(mt0, s0[nt][r]);
                mt1 = fmaxf(mt1, s1[nt][r]);
            }
        mt0 = fmaxf(mt0, __shfl_xor(mt0, 16, 64));
        mt0 = fmaxf(mt0, __shfl_xor(mt0, 32, 64));
        mt1 = fmaxf(mt1, __shfl_xor(mt1, 16, 64));
        mt1 = fmaxf(mt1, __shfl_xor(mt1, 32, 64));

        if (__any((mt0 > m_0 + 11.5f) || (mt1 > m_1 + 11.5f))) {
            float mn0 = fmaxf(m_0, mt0), mn1 = fmaxf(m_1, mt1);
            float a0 = exp2hw(m_0 - mn0), a1 = exp2hw(m_1 - mn1);
            m_0 = mn0; m_1 = mn1;
            l_0 *= a0;  l_1 *= a1;
            float al0[4], al1[4];
            #pragma unroll
            for (int r = 0; r < 4; ++r) {
                al0[r] = __shfl(a0, lg*4 + r, 64);
                al1[r] = __shfl(a1, lg*4 + r, 64);
            }
            #pragma unroll
            for (int dt = 0; dt < 6; ++dt)
                #pragma unroll
                for (int r = 0; r < 4; ++r) {
                    o0[dt][r] *= al0[r];
                    o1[dt][r] *= al1[r];
                }
        }

        float ps0 = 0.f, ps1 = 0.f;
        #pragma unroll
        for (int nt = 0; nt < 4; ++nt)
            #pragma unroll
            for (int r = 0; r < 4; ++r) {
                float p0 = exp2hw(s0[nt][r] - m_0);
                float p1 = exp2hw(s1[nt][r] - m_1);
                s0[nt][r] = p0; ps0 += p0;
                s1[nt][r] = p1; ps1 += p1;
            }
        ps0 += __shfl_xor(ps0, 16, 64);
        ps0 += __shfl_xor(ps0, 32, 64);
        ps1 += __shfl_xor(ps1, 16, 64);
        ps1 += __shfl_xor(ps1, 32, 64);
        l_0 += ps0;
        l_1 += ps1;

        // ---- pack P^T rows ----
        #pragma unroll
        for (int nt = 0; nt < 4; ++nt) {
            uint2 pk0, pk1;
            pk0.x = cvtpk(s0[nt][0], s0[nt][1]);
            pk0.y = cvtpk(s0[nt][2], s0[nt][3]);
            pk1.x = cvtpk(s1[nt][0], s1[nt][1]);
            pk1.y = cvtpk(s1[nt][2], s1[nt][3]);
            *(uint2*)&PsT[w][l15][nt*16 + lg*4]      = pk0;
            *(uint2*)&PsT[w][16 + l15][nt*16 + lg*4] = pk1;
        }

        // ---- O += P V ----
        short8v a00 = *(const short8v*)&PsT[w][l15][lg*8];
        short8v a01 = *(const short8v*)&PsT[w][l15][32 + lg*8];
        short8v a10 = *(const short8v*)&PsT[w][16 + l15][lg*8];
        short8v a11 = *(const short8v*)&PsT[w][16 + l15][32 + lg*8];
        __builtin_amdgcn_s_setprio(1);
        #pragma unroll
        for (int dt = 0; dt < 6; ++dt) {
            short8v bv0 = *(const short8v*)((const char*)Vs + dt*2048 + l15*128 + tV[0]);
            short8v bv1 = *(const short8v*)((const char*)Vs + dt*2048 + l15*128 + tV[1]);
            o0[dt] = __builtin_amdgcn_mfma_f32_16x16x32_bf16(a00, bv0, o0[dt], 0, 0, 0);
            o0[dt] = __builtin_amdgcn_mfma_f32_16x16x32_bf16(a01, bv1, o0[dt], 0, 0, 0);
            o1[dt] = __builtin_amdgcn_mfma_f32_16x16x32_bf16(a10, bv0, o1[dt], 0, 0, 0);
            o1[dt] = __builtin_amdgcn_mfma_f32_16x16x32_bf16(a11, bv1, o1[dt], 0, 0, 0);
        }
        __builtin_amdgcn_s_setprio(0);
        __syncthreads();

        if (t + 1 < NT) {
            #pragma unroll
            for (int j = 0; j < 3; ++j) {
                *(short8v*)((char*)Ks + kdst[j]) = kreg[j];
                *(short8v*)((char*)Vs + vdst[j]) = vreg[j];
            }
        }
        __syncthreads();
    }

    // ---- epilogue: unnormalized bf16 partials ----
    ushort* ob = opb + (((size_t)sc * BH + bh) * LQ + qt*QB + w*32) * HD;
    #pragma unroll
    for (int r = 0; r < 4; ++r) {
        #pragma unroll
        for (int dt = 0; dt < 6; ++dt) {
            ob[(size_t)(lg*4 + r) * HD + dt*16 + l15]      = f2bf(o0[dt][r]);
            ob[(size_t)(16 + lg*4 + r) * HD + dt*16 + l15] = f2bf(o1[dt][r]);
        }
    }
    if (lane < 16) {
        size_t mlrow = ((size_t)sc * BH + bh) * LQ + qt*QB + w*32 + lane;
        mlb[mlrow*2 + 0] = m_0;
        mlb[mlrow*2 + 1] = l_0;
        mlb[(mlrow + 16)*2 + 0] = m_1;
        mlb[(mlrow + 16)*2 + 1] = l_1;
    }
}

// merge KVS=4 bf16 partials -> ctx bf16 (B, LQ, 768); m,l in log2 domain
__global__ __launch_bounds__(256)
void combine(const ushort* __restrict__ opb, const float* __restrict__ mlb,
             ushort* __restrict__ ctx)
{
    const int NROW = BH * LQ;
    int idx = blockIdx.x * 256 + threadIdx.x;
    int row = idx / 12, seg = idx % 12;

    float m[KVS], lv[KVS];
    #pragma unroll
    for (int i = 0; i < KVS; ++i) {
        m[i]  = mlb[((size_t)i*NROW + row)*2 + 0];
        lv[i] = mlb[((size_t)i*NROW + row)*2 + 1];
    }
    float ms = m[0];
    #pragma unroll
    for (int i = 1; i < KVS; ++i) ms = fmaxf(ms, m[i]);
    float wsum = 0.f, wgt[KVS];
    #pragma unroll
    for (int i = 0; i < KVS; ++i) {
        wgt[i] = exp2hw(m[i] - ms);
        wsum += lv[i] * wgt[i];
    }
    float inv = 1.f / wsum;

    float acc[8] = {};
    #pragma unroll
    for (int i = 0; i < KVS; ++i) {
        uint4 v = *(const uint4*)&opb[((size_t)i*NROW + row)*HD + seg*8];
        uint vv[4] = {v.x, v.y, v.z, v.w};
        #pragma unroll
        for (int j2 = 0; j2 < 4; ++j2) {
            acc[j2*2+0] += bf2f((ushort)(vv[j2] & 0xffff)) * wgt[i];
            acc[j2*2+1] += bf2f((ushort)(vv[j2] >> 16))    * wgt[i];
        }
    }

    int bh = row / LQ, l = row % LQ;
    int b = bh >> 3, h = bh & 7;
    ushort* o = ctx + ((size_t)b * LQ + l) * DM + h * HD + seg*8;
    uint4 pk;
    pk.x = cvtpk(acc[0]*inv, acc[1]*inv);
    pk.y = cvtpk(acc[2]*inv, acc[3]*inv);
    pk.z = cvtpk(acc[4]*inv, acc[5]*inv);
    pk.w = cvtpk(acc[6]*inv, acc[7]*inv);
    *(uint4*)o = pk;
}

extern "C" void kernel_launch(void* const* d_in, const int* in_sizes, int n_in,
                              void* d_out, int out_size, void* d_ws, size_t ws_size,
                              hipStream_t stream)
{
    const float* query = (const float*)d_in[0];
    const float* key   = (const float*)d_in[1];
    const float* value = (const float*)d_in[2];
    const float* cq    = (const float*)d_in[3];
    const float* ck    = (const float*)d_in[4];
    const float* Wq    = (const float*)d_in[5];
    const float* bqv   = (const float*)d_in[6];
    const float* Wk    = (const float*)d_in[7];
    const float* bkv   = (const float*)d_in[8];
    const float* Wv    = (const float*)d_in[9];
    const float* bvv   = (const float*)d_in[10];
    const float* Wo    = (const float*)d_in[11];
    const float* bov   = (const float*)d_in[12];
    float* out = (float*)d_out;

    const size_t NQ = (size_t)BQ * LQ * DM;   // 3,145,728
    const size_t NK = (size_t)BQ * LK * DM;   // 12,582,912
    const size_t NP = (size_t)KVS * BH * LQ * HD;  // 12,582,912 partial elems

    ushort* wq  = (ushort*)d_ws;        // 4 weight matrices contiguous
    ushort* wk  = wq  + NW;
    ushort* wv  = wk  + NW;
    ushort* wo  = wv  + NW;
    ushort* qws = wo  + NW;             // q bf16 (B,H,LQ,96)
    ushort* kws = qws + NQ;             // k bf16 (B,H,LK,96)
    ushort* vtb = kws + NK;             // v^T bf16 (B,H,96,LK)
    ushort* opb = vtb + NK;             // bf16 partials
    ushort* ctx = opb + NP;             // ctx bf16 (B,LQ,768)
    float*  mlb = (float*)(ctx + NQ);   // KVS*BH*LQ*(m,l)
    // total ~94 MB

    wcvt<<<4*(NW/1024), 256, 0, stream>>>(Wq, Wk, Wv, Wo, wq);
    qkv_gemm<<<1728, 256, 0, stream>>>(query, key, value, wq, wk, wv,
                                       bqv, bkv, bvv, cq, ck, qws, kws, vtb);
    attn_mfma<<<(LQ/QB) * BH * KVS, 256, 0, stream>>>(qws, kws, vtb, opb, mlb);
    combine<<<BH*LQ*12/256, 256, 0, stream>>>(opb, mlb, ctx);
    gemm_out<<<(BQ*LQ/128)*6, 256, 0, stream>>>(ctx, wo, bov, out);
}